// Round 1
// baseline (19036.707 us; speedup 1.0000x reference)
//
#include <hip/hip_runtime.h>
#include <math.h>

// DreamBeliefTracker — round 5: persistent-scan kernel.
//  * Round-4 measured 93.4 µs/step; modeled kernel work is only ~25-30 µs/step.
//    The gap is 6 serialized launch boundaries per step (dispatch + drain + L2
//    flush ~10 µs each). This round fuses the entire 64-step scan into ONE
//    kernel with device-scope counter barriers (6 gsyncs/step, ~1-3 µs each).
//  * All phase arithmetic is IDENTICAL (bit-exact) to round 4: same f16 hi/lo
//    planes, same tile decomposition, same reduction orders. k_sample is
//    re-laid-out for 256-thread blocks (4 chunks, same 32-lane shfl groups).
//  * Grid = occupancy_per_CU * num_CUs (capped at 512), so all blocks are
//    co-resident; barrier uses a monotonic counter (re-zeroed in-graph each
//    replay) + release/acquire agent-scope atomics; spin guard avoids hangs.

typedef _Float16 f16;
typedef _Float16 f16x8 __attribute__((ext_vector_type(8)));
typedef float f32x4 __attribute__((ext_vector_type(4)));

constexpr int kB = 256, kN1 = 1024, kG3N = 3072, kActD = 6, kT = 64;
constexpr float kLoScale = 4096.f;
constexpr float kLoInv = 1.f / 4096.f;

__device__ __forceinline__ void wr_planes(f16* hi, f16* lo, size_t i, float x) {
  f16 h = (f16)x;
  hi[i] = h;
  lo[i] = (f16)((x - (float)h) * kLoScale);
}

__device__ __forceinline__ void glds16(const f16* g, f16* l) {
  __builtin_amdgcn_global_load_lds(
      (const __attribute__((address_space(1))) unsigned int*)g,
      (__attribute__((address_space(3))) unsigned int*)l, 16, 0, 0);
}

// ---------------------------------------------------------- shared LDS union
struct GemmLDS { f16 As[2][2][8][64][8]; f16 Ws[2][2][4][64][8]; };  // 48 KB
struct GruLDS  { float sh[kG3N]; float red[8]; };                    // 12.3 KB
struct SmpLDS  { float skl[32]; int sidx[32]; };                     // 256 B
union ScanLDS  { GemmLDS g; GruLDS r; SmpLDS s; };

// ------------------------------------------------------------- MFMA GEMM ----
// 256 threads (4 waves, 2m x 2n), tile 128x64, BK=32, double-buffered
// global_load_lds prefetch. A from up to two concatenated hi/lo plane sources
// (row-major [m][k]); W transposed planes [n][K]. fp32 out. (verbatim round-4)
__device__ void dev_mgemm(GemmLDS& L, const f16* A1h, const f16* A1l,
                          const f16* A2h, const f16* A2l,
                          const f16* Wph, const f16* Wpl, float* outF,
                          int cols1, int K, int Nout, int k0, int klen,
                          int bx, int by) {
  const int m0 = bx * 128, n0 = by * 64;
  const int tid = threadIdx.x, wave = tid >> 6, lane = tid & 63;
  const int rlo = lane & 15, khi = (lane >> 4) * 8;
  const int wmf = (wave & 1) * 4, wnf = (wave >> 1) * 2;

  f32x4 acc1[4][2], acc2[4][2];
#pragma unroll
  for (int i = 0; i < 4; ++i)
#pragma unroll
    for (int j = 0; j < 2; ++j)
#pragma unroll
      for (int r = 0; r < 4; ++r) { acc1[i][j][r] = 0.f; acc2[i][j][r] = 0.f; }

  auto issueTile = [&](int it, int buf) {
    const int kg = k0 + it * 32;
    const f16 *h, *l; int rs, cb;
    if (kg < cols1) { h = A1h; l = A1l; rs = cols1; cb = kg; }
    else { h = A2h; l = A2l; rs = K - cols1; cb = kg - cols1; }
#pragma unroll
    for (int i = 0; i < 2; ++i) {
      const int mf = wave * 2 + i;
      const size_t go = (size_t)(m0 + mf * 16 + rlo) * rs + cb + khi;
      glds16(h + go, &L.As[buf][0][mf][0][0]);
      glds16(l + go, &L.As[buf][1][mf][0][0]);
    }
    const size_t wo = (size_t)(n0 + wave * 16 + rlo) * K + kg + khi;
    glds16(Wph + wo, &L.Ws[buf][0][wave][0][0]);
    glds16(Wpl + wo, &L.Ws[buf][1][wave][0][0]);
  };

  issueTile(0, 0);
  __syncthreads();
  const int niter = klen >> 5;
#pragma unroll 1
  for (int it = 0; it < niter; ++it) {
    const int buf = it & 1;
    if (it + 1 < niter) issueTile(it + 1, buf ^ 1);
    f16x8 Af[4][2], Wf[2][2];
#pragma unroll
    for (int mf = 0; mf < 4; ++mf) {
      Af[mf][0] = *(const f16x8*)&L.As[buf][0][wmf + mf][lane][0];
      Af[mf][1] = *(const f16x8*)&L.As[buf][1][wmf + mf][lane][0];
    }
#pragma unroll
    for (int nf = 0; nf < 2; ++nf) {
      Wf[nf][0] = *(const f16x8*)&L.Ws[buf][0][wnf + nf][lane][0];
      Wf[nf][1] = *(const f16x8*)&L.Ws[buf][1][wnf + nf][lane][0];
    }
#pragma unroll
    for (int mf = 0; mf < 4; ++mf)
#pragma unroll
      for (int nf = 0; nf < 2; ++nf) {
        acc1[mf][nf] = __builtin_amdgcn_mfma_f32_16x16x32_f16(Af[mf][0], Wf[nf][0], acc1[mf][nf], 0, 0, 0);
        acc2[mf][nf] = __builtin_amdgcn_mfma_f32_16x16x32_f16(Af[mf][0], Wf[nf][1], acc2[mf][nf], 0, 0, 0);
        acc2[mf][nf] = __builtin_amdgcn_mfma_f32_16x16x32_f16(Af[mf][1], Wf[nf][0], acc2[mf][nf], 0, 0, 0);
      }
    __syncthreads();
  }
  const int orow = m0 + (wave & 1) * 64, ocol = n0 + (wave >> 1) * 32;
#pragma unroll
  for (int mf = 0; mf < 4; ++mf)
#pragma unroll
    for (int nf = 0; nf < 2; ++nf)
#pragma unroll
      for (int r = 0; r < 4; ++r) {
        const int row = orow + mf * 16 + (lane >> 4) * 4 + r;
        const int col = ocol + nf * 16 + rlo;
        outF[(size_t)row * Nout + col] = acc1[mf][nf][r] + acc2[mf][nf][r] * kLoInv;
      }
}

// --------- LayerNorm + GRU (sums 4 gate partials) + next-step obs staging ---
__device__ void dev_gru(GruLDS& G, int b, const float* Pg, const float* bfused,
                        const float* lns, const float* lnb, float* bbuf,
                        f16* bh, f16* bl, const float* obs_next,
                        f16* oh, f16* ol, int do_obs) {
  const int tid = threadIdx.x;
  const size_t S3 = (size_t)kB * kG3N;
  float v[12];
  float sum = 0.f, sq = 0.f;
#pragma unroll
  for (int i = 0; i < 12; ++i) {
    const int j = tid + i * 256;
    const size_t o = (size_t)b * kG3N + j;
    const float s = Pg[o] + Pg[S3 + o] + Pg[2 * S3 + o] + Pg[3 * S3 + o] + bfused[j];
    v[i] = s; sum += s; sq += s * s;
  }
  if (do_obs) {
#pragma unroll
    for (int i = 0; i < 4; ++i) {
      const int j = tid + i * 256;
      wr_planes(oh, ol, (size_t)b * kN1 + j, obs_next[(size_t)b * kN1 + j]);
    }
  }
  for (int m = 1; m <= 32; m <<= 1) { sum += __shfl_xor(sum, m); sq += __shfl_xor(sq, m); }
  if ((tid & 63) == 0) { G.red[(tid >> 6) * 2] = sum; G.red[(tid >> 6) * 2 + 1] = sq; }
  __syncthreads();
  float ts = 0.f, tq = 0.f;
  for (int w = 0; w < 4; ++w) { ts += G.red[w * 2]; tq += G.red[w * 2 + 1]; }
  const float mu   = ts * (1.f / kG3N);
  const float var  = tq * (1.f / kG3N) - mu * mu;
  const float rinv = 1.f / sqrtf(var + 1e-3f);
#pragma unroll
  for (int i = 0; i < 12; ++i) {
    const int j = tid + i * 256;
    G.sh[j] = (v[i] - mu) * rinv * lns[j] + lnb[j];
  }
  __syncthreads();
#pragma unroll
  for (int i = 0; i < 4; ++i) {
    const int j = tid + i * 256;
    const float r = G.sh[j], c = G.sh[kN1 + j], u = G.sh[2 * kN1 + j];
    const float reset = 1.f / (1.f + expf(-r));
    const float cand  = tanhf(reset * c);
    const float upd   = 1.f / (1.f + expf(-(u - 1.f)));   // UPDATE_BIAS = -1
    const size_t o = (size_t)b * kN1 + j;
    const float bn = upd * cand + (1.f - upd) * bbuf[o];
    bbuf[o] = bn;
    wr_planes(bh, bl, o, bn);
  }
}

// -- softmax/unimix/KL + Gumbel argmax + fused h1 gather (256-thr version) ---
// Identical per-element arithmetic & identical 32-lane shfl groups as round-4
// (j & 31 == tid & 31 since chunk stride 256 is a multiple of 32).
__device__ void dev_sample(SmpLDS& S, int b, const float* PE,
                           const float* bp2, const float* bo2,
                           const float* unz_t, float* loss_t,
                           const float* Wi1, const float* bi1,
                           const float* act_next, f16* h1h, f16* h1l,
                           int do_gather) {
  const int tid = threadIdx.x;
  const size_t PL = (size_t)kB * kN1;
  __syncthreads();   // protect S.* reuse if a block ever runs 2 tasks
#pragma unroll
  for (int c = 0; c < 4; ++c) {
    const int j = c * 256 + tid;
    const size_t o = (size_t)b * kN1 + j;
    float lp = PE[o] + PE[PL + o] + bp2[j];
    float lo = PE[2 * PL + o] + PE[3 * PL + o] + bo2[j];
    lp = fminf(fmaxf(lp, -20.f), 20.f);
    lo = fminf(fmaxf(lo, -20.f), 20.f);
    float mp = lp, mo = lo;
    for (int m = 1; m <= 16; m <<= 1) { mp = fmaxf(mp, __shfl_xor(mp, m)); mo = fmaxf(mo, __shfl_xor(mo, m)); }
    const float ep = expf(lp - mp), eo = expf(lo - mo);
    float sp = ep, so = eo;
    for (int m = 1; m <= 16; m <<= 1) { sp += __shfl_xor(sp, m); so += __shfl_xor(so, m); }
    const float pp = (ep / sp) * 0.99f + (0.01f / 32.f);
    const float po = (eo / so) * 0.99f + (0.01f / 32.f);
    float kt = po * (logf(po + 1e-8f) - logf(pp + 1e-8f));
    for (int m = 1; m <= 16; m <<= 1) kt += __shfl_xor(kt, m);
    const float u = unz_t[o];
    const float g = -logf(-logf(u + 1e-6f) + 1e-6f);
    float vv = logf(fmaxf(po, 1e-6f)) + g;
    int ii = j & 31;
    for (int m = 1; m <= 16; m <<= 1) {
      const float vo = __shfl_xor(vv, m);
      const int   io = __shfl_xor(ii, m);
      if (vo > vv || (vo == vv && io < ii)) { vv = vo; ii = io; }   // first-max ties
    }
    if ((tid & 31) == 0) { S.skl[j >> 5] = kt; S.sidx[j >> 5] = ii; }
  }
  __syncthreads();
  if (tid == 0) {
    float kl = 0.f;
    for (int gg = 0; gg < 32; ++gg) kl += S.skl[gg];
    const float dl = fmaxf(kl, 0.1f);
    loss_t[b] = 1.0f * dl + 0.1f * dl;
  }
  if (do_gather) {
#pragma unroll
    for (int c = 0; c < 4; ++c) {
      const int j = c * 256 + tid;
      float s = bi1[j];
#pragma unroll
      for (int gg = 0; gg < 32; ++gg)
        s += Wi1[(size_t)(gg * 32 + S.sidx[gg]) * kN1 + j];
#pragma unroll
      for (int k = 0; k < kActD; ++k)
        s += act_next[b * kActD + k] * Wi1[(size_t)(kN1 + k) * kN1 + j];
      s = s * (1.f / (1.f + expf(-s)));
      wr_planes(h1h, h1l, (size_t)b * kN1 + j, s);
    }
  }
}

// -------------------------------------------------------- persistent scan ---
struct ScanArgs {
  const float *obs, *acts, *unz;
  float* out;
  const float *lns, *lnb, *bp1, *bo1, *bp2, *bo2, *Wi1, *bi1;
  float *Pg, *PD, *PE, *bbuf, *bfused;
  const f16 *WfTh, *WfTl, *WgBh, *WgBl;
  const f16 *Wp1Th, *Wp1Tl, *Wo1Th, *Wo1Tl, *Wp2Th, *Wp2Tl, *Wo2Th, *Wo2Tl;
  f16 *h1h, *h1l, *bh, *bl, *hph, *hpl, *hoh, *hol, *o0h, *o0l, *o1h, *o1l;
  int* cnt;
  int NB;
};

__device__ __forceinline__ void gsync_impl(int* cnt, int tgt) {
  __syncthreads();                  // all block threads done with phase work
  if (threadIdx.x == 0) {
    __threadfence();                // publish this block's writes device-wide
    __hip_atomic_fetch_add(cnt, 1, __ATOMIC_RELEASE, __HIP_MEMORY_SCOPE_AGENT);
    int guard = 0;
    while (__hip_atomic_load(cnt, __ATOMIC_RELAXED, __HIP_MEMORY_SCOPE_AGENT) < tgt) {
      __builtin_amdgcn_s_sleep(2);
      if (++guard > (1 << 26)) break;   // never hit unless broken; avoids hang
    }
    __threadfence();                // acquire side: invalidate stale caches
  }
  __syncthreads();
}

__global__ __launch_bounds__(256, 2) void k_scan(ScanArgs a) {
  __shared__ ScanLDS L;
  const int NB = a.NB;
  const size_t PL = (size_t)kB * kN1;
  const size_t S3 = (size_t)kB * kG3N;
  int syncno = 0;

#pragma unroll 1
  for (int t = 0; t < kT; ++t) {
    const f16* oth = (t & 1) ? a.o1h : a.o0h;
    const f16* otl = (t & 1) ? a.o1l : a.o0l;
    f16* onh = (t & 1) ? a.o0h : a.o1h;
    f16* onl = (t & 1) ? a.o0l : a.o1l;

    // phase 1: gates — Pg[0..1] = h1 @ WfT (splitK2); Pg[2..3] = b @ WgB (splitK2)
#pragma unroll 1
    for (int task = blockIdx.x; task < 384; task += NB) {
      const int j = task / 96, r = task % 96, bx = r & 1, by = r >> 1;
      const bool top = (j < 2);
      dev_mgemm(L.g, top ? a.h1h : a.bh, top ? a.h1l : a.bl, nullptr, nullptr,
                top ? a.WfTh : a.WgBh, top ? a.WfTl : a.WgBl,
                a.Pg + (size_t)j * S3, 1024, 1024, kG3N, (j & 1) * 512, 512, bx, by);
    }
    gsync_impl(a.cnt, ++syncno * NB);

    // phase 2: LN + GRU + stage next-step obs planes
#pragma unroll 1
    for (int b = blockIdx.x; b < kB; b += NB)
      dev_gru(L.r, b, a.Pg, a.bfused, a.lns, a.lnb, a.bbuf, a.bh, a.bl,
              a.obs + (size_t)(t + 1) * kB * kN1, onh, onl, (t < kT - 1) ? 1 : 0);
    gsync_impl(a.cnt, ++syncno * NB);

    // phase 3: D — PD[0..1] = b @ Wp1T (splitK2); PD[2..5] = [obs,b] @ Wo1T (splitK4)
#pragma unroll 1
    for (int task = blockIdx.x; task < 192; task += NB) {
      const int j = task >> 5, r = task & 31, bx = r & 1, by = r >> 1;
      const f16 *Ah, *Al, *A2h = nullptr, *A2l = nullptr, *Wh, *Wl;
      int K, k0;
      if (j < 2) { Ah = a.bh; Al = a.bl; Wh = a.Wp1Th; Wl = a.Wp1Tl; K = 1024; k0 = j * 512; }
      else { Ah = oth; Al = otl; A2h = a.bh; A2l = a.bl; Wh = a.Wo1Th; Wl = a.Wo1Tl; K = 2048; k0 = (j - 2) * 512; }
      dev_mgemm(L.g, Ah, Al, A2h, A2l, Wh, Wl,
                a.PD + (size_t)j * PL, 1024, K, kN1, k0, 512, bx, by);
    }
    gsync_impl(a.cnt, ++syncno * NB);

    // phase 4: combine — hp = silu(sum2 + bp1); ho = silu(sum4 + bo1)
#pragma unroll 1
    for (int idx = blockIdx.x; idx < 2048; idx += NB) {
      const int by = idx >> 10;
      const int i = (idx & 1023) * 256 + (int)threadIdx.x;
      const float* P = by ? (a.PD + 2 * PL) : a.PD;
      const int np = by ? 4 : 2;
      const float* bias = by ? a.bo1 : a.bp1;
      f16* oh = by ? a.hoh : a.hph;
      f16* ol = by ? a.hol : a.hpl;
      float s = 0.f;
      for (int p = 0; p < np; ++p) s += P[(size_t)p * PL + i];
      s += bias[i & (kN1 - 1)];
      s = s * (1.f / (1.f + expf(-s)));
      wr_planes(oh, ol, i, s);
    }
    gsync_impl(a.cnt, ++syncno * NB);

    // phase 5: E — PE[0..1] = hp @ Wp2T; PE[2..3] = ho @ Wo2T (splitK2 each)
#pragma unroll 1
    for (int task = blockIdx.x; task < 128; task += NB) {
      const int j = task >> 5, r = task & 31, bx = r & 1, by = r >> 1;
      const bool pr = (j < 2);
      dev_mgemm(L.g, pr ? a.hph : a.hoh, pr ? a.hpl : a.hol, nullptr, nullptr,
                pr ? a.Wp2Th : a.Wo2Th, pr ? a.Wp2Tl : a.Wo2Tl,
                a.PE + (size_t)j * PL, 1024, 1024, kN1, (j & 1) * 512, 512, bx, by);
    }
    gsync_impl(a.cnt, ++syncno * NB);

    // phase 6: sample + KL loss + next-step h1 gather
#pragma unroll 1
    for (int b = blockIdx.x; b < kB; b += NB)
      dev_sample(L.s, b, a.PE, a.bp2, a.bo2, a.unz + (size_t)t * PL,
                 a.out + (size_t)t * kB, a.Wi1, a.bi1,
                 a.acts + (size_t)(t + 1) * kB * kActD, a.h1h, a.h1l,
                 (t < kT - 1) ? 1 : 0);
    gsync_impl(a.cnt, ++syncno * NB);
  }
}

// ------------------------------------------------------------- prologue -----
struct MJob {
  const f16 *A1h, *A1l, *A2h, *A2l;
  const f16 *Wph, *Wpl;
  float* outF;
  int cols1, K, Nout, k0, klen, ny;
};
struct MJobs { MJob j[6]; };

__global__ __launch_bounds__(256, 2) void k_mgemm(MJobs js) {
  const MJob jb = js.j[blockIdx.z];
  if ((int)blockIdx.y >= jb.ny) return;
  __shared__ GemmLDS L;
  dev_mgemm(L, jb.A1h, jb.A1l, jb.A2h, jb.A2l, jb.Wph, jb.Wpl, jb.outF,
            jb.cols1, jb.K, jb.Nout, jb.k0, jb.klen, blockIdx.x, blockIdx.y);
}

__global__ __launch_bounds__(256) void k_conv(const float* src, f16* dh, f16* dl) {
  const size_t i = (size_t)blockIdx.x * 256 + threadIdx.x;
  wr_planes(dh, dl, i, src[i]);
}

__global__ __launch_bounds__(256) void k_convT(const float* src, int rowoff, int srcN,
                                               int K, f16* dh, f16* dl) {
  __shared__ float T[64][65];
  const int k0 = blockIdx.x * 64, n0 = blockIdx.y * 64;
  const int tx = threadIdx.x & 63, ty = threadIdx.x >> 6;
#pragma unroll 4
  for (int i = 0; i < 16; ++i) {
    const int k = ty * 16 + i;
    T[k][tx] = src[(size_t)(rowoff + k0 + k) * srcN + n0 + tx];
  }
  __syncthreads();
#pragma unroll 4
  for (int i = 0; i < 16; ++i) {
    const int n = ty * 16 + i;
    const float x = T[tx][n];
    const size_t o = (size_t)(n0 + n) * K + k0 + tx;
    f16 h = (f16)x;
    dh[o] = h;
    dl[o] = (f16)((x - (float)h) * kLoScale);
  }
}

__global__ __launch_bounds__(256) void k_bfused(const float* Wg, const float* bi2, float* bf) {
  const int n = blockIdx.x * 256 + threadIdx.x;
  float s = 0.f;
  for (int j = 0; j < 1024; ++j) s += bi2[j] * Wg[(size_t)j * kG3N + n];
  bf[n] = s;
}

__global__ __launch_bounds__(256) void k_setup(const float* b0, float* bbuf, f16* bh, f16* bl) {
  const size_t i = (size_t)blockIdx.x * 256 + threadIdx.x;
  const float b = b0[i];
  bbuf[i] = b;
  wr_planes(bh, bl, i, b);
}

__global__ void k_zero(int* p) {
  if (threadIdx.x == 0 && blockIdx.x == 0) *p = 0;
}

__global__ __launch_bounds__(256) void k_finish0(const float* P, const float* Wi1,
    const float* bi1, const float* act0, f16* h1h, f16* h1l) {
  const int b = blockIdx.y;
  const int j = blockIdx.x * 256 + threadIdx.x;
  __shared__ float sact[kActD];
  if (threadIdx.x < kActD) sact[threadIdx.x] = act0[b * kActD + threadIdx.x];
  __syncthreads();
  float s = P[(size_t)b * kN1 + j] + bi1[j];
#pragma unroll
  for (int k = 0; k < kActD; ++k) s += sact[k] * Wi1[(size_t)(kN1 + k) * kN1 + j];
  s = s * (1.f / (1.f + expf(-s)));
  wr_planes(h1h, h1l, (size_t)b * kN1 + j, s);
}

// ---------------------------------------------------------------------------
extern "C" void kernel_launch(void* const* d_in, const int* in_sizes, int n_in,
                              void* d_out, int out_size, void* d_ws, size_t ws_size,
                              hipStream_t stream) {
  const float* b0   = (const float*)d_in[0];
  const float* z0   = (const float*)d_in[1];
  const float* acts = (const float*)d_in[2];
  const float* obs  = (const float*)d_in[3];
  const float* unz  = (const float*)d_in[4];
  const float* Wi1  = (const float*)d_in[5];
  const float* bi1  = (const float*)d_in[6];
  const float* Wi2  = (const float*)d_in[7];
  const float* bi2  = (const float*)d_in[8];
  const float* Wg   = (const float*)d_in[9];
  const float* lns  = (const float*)d_in[10];
  const float* lnb  = (const float*)d_in[11];
  const float* Wo1  = (const float*)d_in[12];
  const float* bo1  = (const float*)d_in[13];
  const float* Wo2  = (const float*)d_in[14];
  const float* bo2  = (const float*)d_in[15];
  const float* Wp1  = (const float*)d_in[16];
  const float* bp1  = (const float*)d_in[17];
  const float* Wp2  = (const float*)d_in[18];
  const float* bp2  = (const float*)d_in[19];
  float* out = (float*)d_out;

  char* wsb = (char*)d_ws;
  size_t off = 0;
  auto allocB = [&](size_t bytes) { char* p = wsb + off; off += (bytes + 255) & ~(size_t)255; return p; };
  const size_t PL = (size_t)kB * kN1;
  const size_t S3 = (size_t)kB * kG3N;
  const size_t W1 = (size_t)kN1 * kN1;

  // region A: gate partials (4 x 256x3072 fp32 = 12 MB) — overlays Wfused_tmp
  float* Pg = (float*)allocB(4 * S3 * 4);
  float* Wfused_tmp = Pg;
  // region B: WgT planes (prologue-only, 12.6 MB) — overlays PD (6 MB) + PE (4 MB)
  f16* WgTh = (f16*)allocB(W1 * 3 * 2);
  f16* WgTl = (f16*)allocB(W1 * 3 * 2);
  float* PD = (float*)WgTh;
  float* PE = (float*)WgTl;
  // persistent planes / state
  f16* h1h = (f16*)allocB(PL * 2);  f16* h1l = (f16*)allocB(PL * 2);
  f16* bh  = (f16*)allocB(PL * 2);  f16* bl  = (f16*)allocB(PL * 2);
  f16* hph = (f16*)allocB(PL * 2);  f16* hpl = (f16*)allocB(PL * 2);
  f16* hoh = (f16*)allocB(PL * 2);  f16* hol = (f16*)allocB(PL * 2);
  f16* o0h = (f16*)allocB(PL * 2);  f16* o0l = (f16*)allocB(PL * 2);
  f16* o1h = (f16*)allocB(PL * 2);  f16* o1l = (f16*)allocB(PL * 2);
  f16* z0h = (f16*)allocB(PL * 2);  f16* z0l = (f16*)allocB(PL * 2);
  float* bbuf   = (float*)allocB(PL * 4);
  float* bfused = (float*)allocB((size_t)kG3N * 4);
  // weight planes
  f16* WfTh = (f16*)allocB(W1 * 3 * 2);  f16* WfTl = (f16*)allocB(W1 * 3 * 2);
  f16* WgBh = (f16*)allocB(W1 * 3 * 2);  f16* WgBl = (f16*)allocB(W1 * 3 * 2);
  f16* Wi2h = (f16*)allocB(W1 * 2);      f16* Wi2l = (f16*)allocB(W1 * 2);
  f16* Wi1Th = (f16*)allocB(W1 * 2);     f16* Wi1Tl = (f16*)allocB(W1 * 2);
  f16* Wo1Th = (f16*)allocB(W1 * 2 * 2); f16* Wo1Tl = (f16*)allocB(W1 * 2 * 2);
  f16* Wp1Th = (f16*)allocB(W1 * 2);     f16* Wp1Tl = (f16*)allocB(W1 * 2);
  f16* Wp2Th = (f16*)allocB(W1 * 2);     f16* Wp2Tl = (f16*)allocB(W1 * 2);
  f16* Wo2Th = (f16*)allocB(W1 * 2);     f16* Wo2Tl = (f16*)allocB(W1 * 2);
  int* cnt = (int*)allocB(256);

  // grid size: all blocks must be co-resident for the counter barrier.
  static int s_nb = 0;
  if (s_nb == 0) {
    int dev = 0;
    (void)hipGetDevice(&dev);
    int cu = 0;
    if (hipDeviceGetAttribute(&cu, hipDeviceAttributeMultiprocessorCount, dev) != hipSuccess || cu <= 0)
      cu = 256;
    int occ = 0;
    if (hipOccupancyMaxActiveBlocksPerMultiprocessor(&occ, k_scan, 256, 0) != hipSuccess || occ < 1)
      occ = 1;
    long nb = (long)occ * (long)cu;
    if (nb > 512) nb = 512;
    if (nb < 64) nb = 64;
    s_nb = (int)nb;
  }
  const int NB = s_nb;

  // ================= prologue (unchanged from round 4) =================
  k_convT<<<dim3(16, 48), 256, 0, stream>>>(Wg, 0, kG3N, 1024, WgTh, WgTl);
  k_convT<<<dim3(16, 48), 256, 0, stream>>>(Wg, 1024, kG3N, 1024, WgBh, WgBl);
  k_convT<<<dim3(16, 16), 256, 0, stream>>>(Wi1, 0, kN1, 1024, Wi1Th, Wi1Tl);
  k_convT<<<dim3(32, 16), 256, 0, stream>>>(Wo1, 0, kN1, 2048, Wo1Th, Wo1Tl);
  k_convT<<<dim3(16, 16), 256, 0, stream>>>(Wp1, 0, kN1, 1024, Wp1Th, Wp1Tl);
  k_convT<<<dim3(16, 16), 256, 0, stream>>>(Wp2, 0, kN1, 1024, Wp2Th, Wp2Tl);
  k_convT<<<dim3(16, 16), 256, 0, stream>>>(Wo2, 0, kN1, 1024, Wo2Th, Wo2Tl);
  k_conv<<<dim3(4096), 256, 0, stream>>>(Wi2, Wi2h, Wi2l);
  k_bfused<<<dim3(12), 256, 0, stream>>>(Wg, bi2, bfused);
  {  // Wfused = Wi2 @ WgTop (fp32 into overlay of Pg)
    MJobs J{};
    J.j[0] = { Wi2h, Wi2l, nullptr, nullptr, WgTh, WgTl, Wfused_tmp, 1024, 1024, kG3N, 0, 1024, 48 };
    k_mgemm<<<dim3(8, 48, 1), 256, 0, stream>>>(J);
  }
  k_convT<<<dim3(16, 48), 256, 0, stream>>>(Wfused_tmp, 0, kG3N, 1024, WfTh, WfTl);
  // WgT region dead from here -> PD/PE reuse it
  k_setup<<<dim3(1024), 256, 0, stream>>>(b0, bbuf, bh, bl);
  k_conv<<<dim3(1024), 256, 0, stream>>>(z0, z0h, z0l);
  k_conv<<<dim3(1024), 256, 0, stream>>>(obs, o0h, o0l);    // obs[0]
  k_zero<<<dim3(1), 64, 0, stream>>>(cnt);
  {  // h1(t=0): z0 @ Wi1Top -> PD, then finisher
    MJobs J{};
    J.j[0] = { z0h, z0l, nullptr, nullptr, Wi1Th, Wi1Tl, PD, 1024, 1024, kN1, 0, 1024, 16 };
    k_mgemm<<<dim3(2, 16, 1), 256, 0, stream>>>(J);
  }
  k_finish0<<<dim3(4, kB), 256, 0, stream>>>(PD, Wi1, bi1, acts, h1h, h1l);

  // ================= the scan: ONE persistent kernel =================
  ScanArgs A;
  A.obs = obs; A.acts = acts; A.unz = unz; A.out = out;
  A.lns = lns; A.lnb = lnb; A.bp1 = bp1; A.bo1 = bo1; A.bp2 = bp2; A.bo2 = bo2;
  A.Wi1 = Wi1; A.bi1 = bi1;
  A.Pg = Pg; A.PD = PD; A.PE = PE; A.bbuf = bbuf; A.bfused = bfused;
  A.WfTh = WfTh; A.WfTl = WfTl; A.WgBh = WgBh; A.WgBl = WgBl;
  A.Wp1Th = Wp1Th; A.Wp1Tl = Wp1Tl; A.Wo1Th = Wo1Th; A.Wo1Tl = Wo1Tl;
  A.Wp2Th = Wp2Th; A.Wp2Tl = Wp2Tl; A.Wo2Th = Wo2Th; A.Wo2Tl = Wo2Tl;
  A.h1h = h1h; A.h1l = h1l; A.bh = bh; A.bl = bl;
  A.hph = hph; A.hpl = hpl; A.hoh = hoh; A.hol = hol;
  A.o0h = o0h; A.o0l = o0l; A.o1h = o1h; A.o1l = o1l;
  A.cnt = cnt; A.NB = NB;
  k_scan<<<dim3(NB), dim3(256), 0, stream>>>(A);
}

// Round 3
// 12008.976 us; speedup vs baseline: 1.5852x; 1.5852x over previous
//
#include <hip/hip_runtime.h>
#include <math.h>

// DreamBeliefTracker — round 7: hardened fence-free persistent scan.
//  * Round-5 (working but slow, 19 ms): gsync's release/acquire fences emitted
//    per-block buffer_wbl2+buffer_inv — L2 flushed 384x, weights re-streamed.
//  * Round-6 (container failed; infra suspect): fence-free MALL coherence.
//  * Round-7 = round-6 with hazards removed:
//      - no-wait inline-asm loads -> __hip_atomic_load(RELAXED, AGENT)
//        (compiler-tracked waitcnt; no spill-of-pending-load hazard)
//      - NB capped at 384 (covers largest phase; fewer barrier arrivals)
//      - finite spin guard (~28 ms/barrier worst case -> fast-fail, no wedge)
//    Coherence model: producers store sc0sc1 (write-through to MALL, the
//    memory-side cross-XCD coherent point); consumers load sc0sc1 (L1/L2
//    bypass); weights stay L2-resident (plain loads; never invalidated).
//    Barrier = s_waitcnt vmcnt(0) (stores ack'd at coherent point) +
//    RELAXED agent counter atomics — zero wbl2/inv instructions.

typedef _Float16 f16;
typedef _Float16 f16x8 __attribute__((ext_vector_type(8)));
typedef float f32x4 __attribute__((ext_vector_type(4)));

constexpr int kB = 256, kN1 = 1024, kG3N = 3072, kActD = 6, kT = 64;
constexpr float kLoScale = 4096.f;
constexpr float kLoInv = 1.f / 4096.f;

// ---- coherent (cross-XCD via MALL) accessors — no fences, no L2 inv ----
__device__ __forceinline__ float lda_sc(const float* p) {
  return __hip_atomic_load(p, __ATOMIC_RELAXED, __HIP_MEMORY_SCOPE_AGENT);
}
__device__ __forceinline__ void stg_sc(float* p, float v) {
  __hip_atomic_store(p, v, __ATOMIC_RELAXED, __HIP_MEMORY_SCOPE_AGENT);
}
__device__ __forceinline__ void sth_sc(f16* p, f16 v) {
  __hip_atomic_store((unsigned short*)p, __builtin_bit_cast(unsigned short, v),
                     __ATOMIC_RELAXED, __HIP_MEMORY_SCOPE_AGENT);
}

__device__ __forceinline__ void wr_planes(f16* hi, f16* lo, size_t i, float x) {
  f16 h = (f16)x;
  hi[i] = h;
  lo[i] = (f16)((x - (float)h) * kLoScale);
}
__device__ __forceinline__ void wr_planes_sc(f16* hi, f16* lo, size_t i, float x) {
  f16 h = (f16)x;
  sth_sc(hi + i, h);
  sth_sc(lo + i, (f16)((x - (float)h) * kLoScale));
}

// weights: normal cacheable DMA.  activations: sc0|sc1 (aux=1|16=17) DMA.
__device__ __forceinline__ void glds16w(const f16* g, f16* l) {
  __builtin_amdgcn_global_load_lds(
      (const __attribute__((address_space(1))) unsigned int*)g,
      (__attribute__((address_space(3))) unsigned int*)l, 16, 0, 0);
}
__device__ __forceinline__ void glds16a(const f16* g, f16* l) {
  __builtin_amdgcn_global_load_lds(
      (const __attribute__((address_space(1))) unsigned int*)g,
      (__attribute__((address_space(3))) unsigned int*)l, 16, 0, 17);
}

// ---------------------------------------------------------- shared LDS union
struct GemmLDS { f16 As[2][2][8][64][8]; f16 Ws[2][2][4][64][8]; };  // 48 KB
struct GruLDS  { float sh[kG3N]; float red[8]; };                    // 12.3 KB
struct SmpLDS  { float skl[32]; int sidx[32]; };                     // 256 B
union ScanLDS  { GemmLDS g; GruLDS r; SmpLDS s; };

// ------------------------------------------------------------- MFMA GEMM ----
// 256 threads (4 waves, 2m x 2n), tile 128x64, BK=32, double-buffered DMA.
// A planes read coherently (sc0sc1 DMA); W planes normal (L2-resident).
// Output written coherently at 64B granule: [(o>>4)*pstride+pidx]*16+(o&15).
__device__ void dev_mgemm(GemmLDS& L, const f16* A1h, const f16* A1l,
                          const f16* A2h, const f16* A2l,
                          const f16* Wph, const f16* Wpl, float* outF,
                          int cols1, int K, int Nout, int k0, int klen,
                          int bx, int by, int pstride, int pidx) {
  const int m0 = bx * 128, n0 = by * 64;
  const int tid = threadIdx.x, wave = tid >> 6, lane = tid & 63;
  const int rlo = lane & 15, khi = (lane >> 4) * 8;
  const int wmf = (wave & 1) * 4, wnf = (wave >> 1) * 2;

  f32x4 acc1[4][2], acc2[4][2];
#pragma unroll
  for (int i = 0; i < 4; ++i)
#pragma unroll
    for (int j = 0; j < 2; ++j)
#pragma unroll
      for (int r = 0; r < 4; ++r) { acc1[i][j][r] = 0.f; acc2[i][j][r] = 0.f; }

  auto issueTile = [&](int it, int buf) {
    const int kg = k0 + it * 32;
    const f16 *h, *l; int rs, cb;
    if (kg < cols1) { h = A1h; l = A1l; rs = cols1; cb = kg; }
    else { h = A2h; l = A2l; rs = K - cols1; cb = kg - cols1; }
#pragma unroll
    for (int i = 0; i < 2; ++i) {
      const int mf = wave * 2 + i;
      const size_t go = (size_t)(m0 + mf * 16 + rlo) * rs + cb + khi;
      glds16a(h + go, &L.As[buf][0][mf][0][0]);
      glds16a(l + go, &L.As[buf][1][mf][0][0]);
    }
    const size_t wo = (size_t)(n0 + wave * 16 + rlo) * K + kg + khi;
    glds16w(Wph + wo, &L.Ws[buf][0][wave][0][0]);
    glds16w(Wpl + wo, &L.Ws[buf][1][wave][0][0]);
  };

  issueTile(0, 0);
  __syncthreads();
  const int niter = klen >> 5;
#pragma unroll 1
  for (int it = 0; it < niter; ++it) {
    const int buf = it & 1;
    if (it + 1 < niter) issueTile(it + 1, buf ^ 1);
    f16x8 Af[4][2], Wf[2][2];
#pragma unroll
    for (int mf = 0; mf < 4; ++mf) {
      Af[mf][0] = *(const f16x8*)&L.As[buf][0][wmf + mf][lane][0];
      Af[mf][1] = *(const f16x8*)&L.As[buf][1][wmf + mf][lane][0];
    }
#pragma unroll
    for (int nf = 0; nf < 2; ++nf) {
      Wf[nf][0] = *(const f16x8*)&L.Ws[buf][0][wnf + nf][lane][0];
      Wf[nf][1] = *(const f16x8*)&L.Ws[buf][1][wnf + nf][lane][0];
    }
#pragma unroll
    for (int mf = 0; mf < 4; ++mf)
#pragma unroll
      for (int nf = 0; nf < 2; ++nf) {
        acc1[mf][nf] = __builtin_amdgcn_mfma_f32_16x16x32_f16(Af[mf][0], Wf[nf][0], acc1[mf][nf], 0, 0, 0);
        acc2[mf][nf] = __builtin_amdgcn_mfma_f32_16x16x32_f16(Af[mf][0], Wf[nf][1], acc2[mf][nf], 0, 0, 0);
        acc2[mf][nf] = __builtin_amdgcn_mfma_f32_16x16x32_f16(Af[mf][1], Wf[nf][0], acc2[mf][nf], 0, 0, 0);
      }
    __syncthreads();
  }
  const int orow = m0 + (wave & 1) * 64, ocol = n0 + (wave >> 1) * 32;
#pragma unroll
  for (int mf = 0; mf < 4; ++mf)
#pragma unroll
    for (int nf = 0; nf < 2; ++nf)
#pragma unroll
      for (int r = 0; r < 4; ++r) {
        const int row = orow + mf * 16 + (lane >> 4) * 4 + r;
        const int col = ocol + nf * 16 + rlo;
        const int o = row * Nout + col;
        float* dst = outF + ((size_t)(o >> 4) * pstride + pidx) * 16 + (o & 15);
        stg_sc(dst, acc1[mf][nf][r] + acc2[mf][nf][r] * kLoInv);
      }
}

// --------- LayerNorm + GRU (sums 4 gate partials) + next-step obs staging ---
__device__ void dev_gru(GruLDS& G, int b, const float* Pg, const float* bfused,
                        const float* lns, const float* lnb, float* bbuf,
                        f16* bh, f16* bl, const float* obs_next,
                        f16* oh, f16* ol, int do_obs) {
  const int tid = threadIdx.x;
  float v[12];
  float sum = 0.f, sq = 0.f;
#pragma unroll
  for (int i = 0; i < 12; ++i) {
    const int j = tid + i * 256;
    const size_t o = (size_t)b * kG3N + j;
    const float* base = Pg + ((o >> 4) * 4) * 16 + (o & 15);
    const float q0 = lda_sc(base),      q1 = lda_sc(base + 16);
    const float q2 = lda_sc(base + 32), q3 = lda_sc(base + 48);
    const float s = (((q0 + q1) + q2) + q3) + bfused[j];
    v[i] = s; sum += s; sq += s * s;
  }
  if (do_obs) {
#pragma unroll
    for (int i = 0; i < 4; ++i) {
      const int j = tid + i * 256;
      wr_planes_sc(oh, ol, (size_t)b * kN1 + j, obs_next[(size_t)b * kN1 + j]);
    }
  }
  for (int m = 1; m <= 32; m <<= 1) { sum += __shfl_xor(sum, m); sq += __shfl_xor(sq, m); }
  if ((tid & 63) == 0) { G.red[(tid >> 6) * 2] = sum; G.red[(tid >> 6) * 2 + 1] = sq; }
  __syncthreads();
  float ts = 0.f, tq = 0.f;
  for (int w = 0; w < 4; ++w) { ts += G.red[w * 2]; tq += G.red[w * 2 + 1]; }
  const float mu   = ts * (1.f / kG3N);
  const float var  = tq * (1.f / kG3N) - mu * mu;
  const float rinv = 1.f / sqrtf(var + 1e-3f);
#pragma unroll
  for (int i = 0; i < 12; ++i) {
    const int j = tid + i * 256;
    G.sh[j] = (v[i] - mu) * rinv * lns[j] + lnb[j];
  }
  __syncthreads();
#pragma unroll
  for (int i = 0; i < 4; ++i) {
    const int j = tid + i * 256;
    const float r = G.sh[j], c = G.sh[kN1 + j], u = G.sh[2 * kN1 + j];
    const float reset = 1.f / (1.f + expf(-r));
    const float cand  = tanhf(reset * c);
    const float upd   = 1.f / (1.f + expf(-(u - 1.f)));   // UPDATE_BIAS = -1
    const size_t o = (size_t)b * kN1 + j;
    const float bn = upd * cand + (1.f - upd) * bbuf[o];
    bbuf[o] = bn;                 // same persistent block every step: plain ok
    wr_planes_sc(bh, bl, o, bn);
  }
}

// -- softmax/unimix/KL + Gumbel argmax + fused h1 gather (256-thr version) ---
__device__ void dev_sample(SmpLDS& S, int b, const float* PE,
                           const float* bp2, const float* bo2,
                           const float* unz_t, float* loss_t,
                           const float* Wi1, const float* bi1,
                           const float* act_next, f16* h1h, f16* h1l,
                           int do_gather) {
  const int tid = threadIdx.x;
  __syncthreads();
#pragma unroll
  for (int c = 0; c < 4; ++c) {
    const int j = c * 256 + tid;
    const int o = b * kN1 + j;
    const float* base = PE + ((size_t)(o >> 4) * 4) * 16 + (o & 15);
    const float e0 = lda_sc(base),      e1 = lda_sc(base + 16);
    const float e2 = lda_sc(base + 32), e3 = lda_sc(base + 48);
    float lp = e0 + e1 + bp2[j];
    float lo = e2 + e3 + bo2[j];
    lp = fminf(fmaxf(lp, -20.f), 20.f);
    lo = fminf(fmaxf(lo, -20.f), 20.f);
    float mp = lp, mo = lo;
    for (int m = 1; m <= 16; m <<= 1) { mp = fmaxf(mp, __shfl_xor(mp, m)); mo = fmaxf(mo, __shfl_xor(mo, m)); }
    const float ep = expf(lp - mp), eo = expf(lo - mo);
    float sp = ep, so = eo;
    for (int m = 1; m <= 16; m <<= 1) { sp += __shfl_xor(sp, m); so += __shfl_xor(so, m); }
    const float pp = (ep / sp) * 0.99f + (0.01f / 32.f);
    const float po = (eo / so) * 0.99f + (0.01f / 32.f);
    float kt = po * (logf(po + 1e-8f) - logf(pp + 1e-8f));
    for (int m = 1; m <= 16; m <<= 1) kt += __shfl_xor(kt, m);
    const float u = unz_t[o];
    const float g = -logf(-logf(u + 1e-6f) + 1e-6f);
    float vv = logf(fmaxf(po, 1e-6f)) + g;
    int ii = j & 31;
    for (int m = 1; m <= 16; m <<= 1) {
      const float vo = __shfl_xor(vv, m);
      const int   io = __shfl_xor(ii, m);
      if (vo > vv || (vo == vv && io < ii)) { vv = vo; ii = io; }   // first-max ties
    }
    if ((tid & 31) == 0) { S.skl[j >> 5] = kt; S.sidx[j >> 5] = ii; }
  }
  __syncthreads();
  if (tid == 0) {
    float kl = 0.f;
    for (int gg = 0; gg < 32; ++gg) kl += S.skl[gg];
    const float dl = fmaxf(kl, 0.1f);
    loss_t[b] = 1.0f * dl + 0.1f * dl;
  }
  if (do_gather) {
#pragma unroll
    for (int c = 0; c < 4; ++c) {
      const int j = c * 256 + tid;
      float s = bi1[j];
#pragma unroll
      for (int gg = 0; gg < 32; ++gg)
        s += Wi1[(size_t)(gg * 32 + S.sidx[gg]) * kN1 + j];
#pragma unroll
      for (int k = 0; k < kActD; ++k)
        s += act_next[b * kActD + k] * Wi1[(size_t)(kN1 + k) * kN1 + j];
      s = s * (1.f / (1.f + expf(-s)));
      wr_planes_sc(h1h, h1l, (size_t)b * kN1 + j, s);
    }
  }
}

// -------------------------------------------------------- persistent scan ---
struct ScanArgs {
  const float *obs, *acts, *unz;
  float* out;
  const float *lns, *lnb, *bp1, *bo1, *bp2, *bo2, *Wi1, *bi1;
  float *Pg, *PD, *PE, *bbuf, *bfused;
  const f16 *WfTh, *WfTl, *WgBh, *WgBl;
  const f16 *Wp1Th, *Wp1Tl, *Wo1Th, *Wo1Tl, *Wp2Th, *Wp2Tl, *Wo2Th, *Wo2Tl;
  f16 *h1h, *h1l, *bh, *bl, *hph, *hpl, *hoh, *hol, *o0h, *o0l, *o1h, *o1l;
  int* cnt;
  int NB;
};

// Fence-free barrier: sc1 write-through stores are globally visible once
// vmcnt retires; counter atomics are RELAXED (no wbl2/inv emitted).
__device__ __forceinline__ void gsync(int* cnt, int tgt) {
  asm volatile("s_waitcnt vmcnt(0)" ::: "memory");   // drain this wave's stores
  __syncthreads();
  if (threadIdx.x == 0) {
    __hip_atomic_fetch_add(cnt, 1, __ATOMIC_RELAXED, __HIP_MEMORY_SCOPE_AGENT);
    int guard = 0;
    while (__hip_atomic_load(cnt, __ATOMIC_RELAXED, __HIP_MEMORY_SCOPE_AGENT) < tgt) {
      __builtin_amdgcn_s_sleep(8);
      if (++guard > (1 << 17)) break;   // ~28 ms worst case: fast-fail, no wedge
    }
  }
  __syncthreads();
}

__global__ __launch_bounds__(256, 2) void k_scan(ScanArgs a) {
  __shared__ ScanLDS L;
  const int NB = a.NB;
  int syncno = 0;

#pragma unroll 1
  for (int t = 0; t < kT; ++t) {
    const f16* oth = (t & 1) ? a.o1h : a.o0h;
    const f16* otl = (t & 1) ? a.o1l : a.o0l;
    f16* onh = (t & 1) ? a.o0h : a.o1h;
    f16* onl = (t & 1) ? a.o0l : a.o1l;

    // phase 1: gates — parts 0/1 = h1 @ WfT (splitK2); parts 2/3 = b @ WgB
#pragma unroll 1
    for (int task = blockIdx.x; task < 384; task += NB) {
      const int j = task / 96, r = task % 96, bx = r & 1, by = r >> 1;
      const bool top = (j < 2);
      dev_mgemm(L.g, top ? a.h1h : a.bh, top ? a.h1l : a.bl, nullptr, nullptr,
                top ? a.WfTh : a.WgBh, top ? a.WfTl : a.WgBl,
                a.Pg, 1024, 1024, kG3N, (j & 1) * 512, 512, bx, by, 4, j);
    }
    gsync(a.cnt, ++syncno * NB);

    // phase 2: LN + GRU + stage next-step obs planes
#pragma unroll 1
    for (int b = blockIdx.x; b < kB; b += NB)
      dev_gru(L.r, b, a.Pg, a.bfused, a.lns, a.lnb, a.bbuf, a.bh, a.bl,
              a.obs + (size_t)(t + 1) * kB * kN1, onh, onl, (t < kT - 1) ? 1 : 0);
    gsync(a.cnt, ++syncno * NB);

    // phase 3: D — parts 0/1 = b @ Wp1T (splitK2); parts 2..5 = [obs,b] @ Wo1T
#pragma unroll 1
    for (int task = blockIdx.x; task < 192; task += NB) {
      const int j = task >> 5, r = task & 31, bx = r & 1, by = r >> 1;
      const f16 *Ah, *Al, *A2h = nullptr, *A2l = nullptr, *Wh, *Wl;
      int K, k0;
      if (j < 2) { Ah = a.bh; Al = a.bl; Wh = a.Wp1Th; Wl = a.Wp1Tl; K = 1024; k0 = j * 512; }
      else { Ah = oth; Al = otl; A2h = a.bh; A2l = a.bl; Wh = a.Wo1Th; Wl = a.Wo1Tl; K = 2048; k0 = (j - 2) * 512; }
      dev_mgemm(L.g, Ah, Al, A2h, A2l, Wh, Wl,
                a.PD, 1024, K, kN1, k0, 512, bx, by, 6, j);
    }
    gsync(a.cnt, ++syncno * NB);

    // phase 4: combine — hp = silu(p0+p1+bp1); ho = silu(p2+p3+p4+p5+bo1)
#pragma unroll 1
    for (int idx = blockIdx.x; idx < 1024; idx += NB) {
      const int i = idx * 256 + (int)threadIdx.x;
      const float* base = a.PD + ((size_t)(i >> 4) * 6) * 16 + (i & 15);
      const float p0 = lda_sc(base),      p1 = lda_sc(base + 16);
      const float p2 = lda_sc(base + 32), p3 = lda_sc(base + 48);
      const float p4 = lda_sc(base + 64), p5 = lda_sc(base + 80);
      float sp = (p0 + p1) + a.bp1[i & (kN1 - 1)];
      sp = sp * (1.f / (1.f + expf(-sp)));
      wr_planes_sc(a.hph, a.hpl, i, sp);
      float so = (((p2 + p3) + p4) + p5) + a.bo1[i & (kN1 - 1)];
      so = so * (1.f / (1.f + expf(-so)));
      wr_planes_sc(a.hoh, a.hol, i, so);
    }
    gsync(a.cnt, ++syncno * NB);

    // phase 5: E — parts 0/1 = hp @ Wp2T; parts 2/3 = ho @ Wo2T (splitK2 each)
#pragma unroll 1
    for (int task = blockIdx.x; task < 128; task += NB) {
      const int j = task >> 5, r = task & 31, bx = r & 1, by = r >> 1;
      const bool pr = (j < 2);
      dev_mgemm(L.g, pr ? a.hph : a.hoh, pr ? a.hpl : a.hol, nullptr, nullptr,
                pr ? a.Wp2Th : a.Wo2Th, pr ? a.Wp2Tl : a.Wo2Tl,
                a.PE, 1024, 1024, kN1, (j & 1) * 512, 512, bx, by, 4, j);
    }
    gsync(a.cnt, ++syncno * NB);

    // phase 6: sample + KL loss + next-step h1 gather
#pragma unroll 1
    for (int b = blockIdx.x; b < kB; b += NB)
      dev_sample(L.s, b, a.PE, a.bp2, a.bo2, a.unz + (size_t)t * kB * kN1,
                 a.out + (size_t)t * kB, a.Wi1, a.bi1,
                 a.acts + (size_t)(t + 1) * kB * kActD, a.h1h, a.h1l,
                 (t < kT - 1) ? 1 : 0);
    gsync(a.cnt, ++syncno * NB);
  }
}

// ------------------------------------------------------------- prologue -----
struct MJob {
  const f16 *A1h, *A1l, *A2h, *A2l;
  const f16 *Wph, *Wpl;
  float* outF;
  int cols1, K, Nout, k0, klen, ny, pstride, pidx;
};
struct MJobs { MJob j[6]; };

__global__ __launch_bounds__(256, 2) void k_mgemm(MJobs js) {
  const MJob jb = js.j[blockIdx.z];
  if ((int)blockIdx.y >= jb.ny) return;
  __shared__ GemmLDS L;
  dev_mgemm(L, jb.A1h, jb.A1l, jb.A2h, jb.A2l, jb.Wph, jb.Wpl, jb.outF,
            jb.cols1, jb.K, jb.Nout, jb.k0, jb.klen, blockIdx.x, blockIdx.y,
            jb.pstride, jb.pidx);
}

__global__ __launch_bounds__(256) void k_conv(const float* src, f16* dh, f16* dl) {
  const size_t i = (size_t)blockIdx.x * 256 + threadIdx.x;
  wr_planes(dh, dl, i, src[i]);
}

__global__ __launch_bounds__(256) void k_convT(const float* src, int rowoff, int srcN,
                                               int K, f16* dh, f16* dl) {
  __shared__ float T[64][65];
  const int k0 = blockIdx.x * 64, n0 = blockIdx.y * 64;
  const int tx = threadIdx.x & 63, ty = threadIdx.x >> 6;
#pragma unroll 4
  for (int i = 0; i < 16; ++i) {
    const int k = ty * 16 + i;
    T[k][tx] = src[(size_t)(rowoff + k0 + k) * srcN + n0 + tx];
  }
  __syncthreads();
#pragma unroll 4
  for (int i = 0; i < 16; ++i) {
    const int n = ty * 16 + i;
    const float x = T[tx][n];
    const size_t o = (size_t)(n0 + n) * K + k0 + tx;
    f16 h = (f16)x;
    dh[o] = h;
    dl[o] = (f16)((x - (float)h) * kLoScale);
  }
}

__global__ __launch_bounds__(256) void k_bfused(const float* Wg, const float* bi2, float* bf) {
  const int n = blockIdx.x * 256 + threadIdx.x;
  float s = 0.f;
  for (int j = 0; j < 1024; ++j) s += bi2[j] * Wg[(size_t)j * kG3N + n];
  bf[n] = s;
}

__global__ __launch_bounds__(256) void k_setup(const float* b0, float* bbuf, f16* bh, f16* bl) {
  const size_t i = (size_t)blockIdx.x * 256 + threadIdx.x;
  const float b = b0[i];
  bbuf[i] = b;
  wr_planes(bh, bl, i, b);
}

__global__ void k_zero(int* p) {
  if (threadIdx.x == 0 && blockIdx.x == 0) *p = 0;
}

__global__ __launch_bounds__(256) void k_finish0(const float* P, const float* Wi1,
    const float* bi1, const float* act0, f16* h1h, f16* h1l) {
  const int b = blockIdx.y;
  const int j = blockIdx.x * 256 + threadIdx.x;
  __shared__ float sact[kActD];
  if (threadIdx.x < kActD) sact[threadIdx.x] = act0[b * kActD + threadIdx.x];
  __syncthreads();
  float s = P[(size_t)b * kN1 + j] + bi1[j];
#pragma unroll
  for (int k = 0; k < kActD; ++k) s += sact[k] * Wi1[(size_t)(kN1 + k) * kN1 + j];
  s = s * (1.f / (1.f + expf(-s)));
  wr_planes(h1h, h1l, (size_t)b * kN1 + j, s);
}

// ---------------------------------------------------------------------------
extern "C" void kernel_launch(void* const* d_in, const int* in_sizes, int n_in,
                              void* d_out, int out_size, void* d_ws, size_t ws_size,
                              hipStream_t stream) {
  const float* b0   = (const float*)d_in[0];
  const float* z0   = (const float*)d_in[1];
  const float* acts = (const float*)d_in[2];
  const float* obs  = (const float*)d_in[3];
  const float* unz  = (const float*)d_in[4];
  const float* Wi1  = (const float*)d_in[5];
  const float* bi1  = (const float*)d_in[6];
  const float* Wi2  = (const float*)d_in[7];
  const float* bi2  = (const float*)d_in[8];
  const float* Wg   = (const float*)d_in[9];
  const float* lns  = (const float*)d_in[10];
  const float* lnb  = (const float*)d_in[11];
  const float* Wo1  = (const float*)d_in[12];
  const float* bo1  = (const float*)d_in[13];
  const float* Wo2  = (const float*)d_in[14];
  const float* bo2  = (const float*)d_in[15];
  const float* Wp1  = (const float*)d_in[16];
  const float* bp1  = (const float*)d_in[17];
  const float* Wp2  = (const float*)d_in[18];
  const float* bp2  = (const float*)d_in[19];
  float* out = (float*)d_out;

  char* wsb = (char*)d_ws;
  size_t off = 0;
  auto allocB = [&](size_t bytes) { char* p = wsb + off; off += (bytes + 255) & ~(size_t)255; return p; };
  const size_t PL = (size_t)kB * kN1;
  const size_t S3 = (size_t)kB * kG3N;
  const size_t W1 = (size_t)kN1 * kN1;

  // region A: gate partials (4 x 256x3072 fp32 = 12 MB) — overlays Wfused_tmp
  float* Pg = (float*)allocB(4 * S3 * 4);
  float* Wfused_tmp = Pg;
  // region B: WgT planes (prologue-only, 12.6 MB) — overlays PD (6 MB) + PE (4 MB)
  f16* WgTh = (f16*)allocB(W1 * 3 * 2);
  f16* WgTl = (f16*)allocB(W1 * 3 * 2);
  float* PD = (float*)WgTh;
  float* PE = (float*)WgTl;
  // persistent planes / state
  f16* h1h = (f16*)allocB(PL * 2);  f16* h1l = (f16*)allocB(PL * 2);
  f16* bh  = (f16*)allocB(PL * 2);  f16* bl  = (f16*)allocB(PL * 2);
  f16* hph = (f16*)allocB(PL * 2);  f16* hpl = (f16*)allocB(PL * 2);
  f16* hoh = (f16*)allocB(PL * 2);  f16* hol = (f16*)allocB(PL * 2);
  f16* o0h = (f16*)allocB(PL * 2);  f16* o0l = (f16*)allocB(PL * 2);
  f16* o1h = (f16*)allocB(PL * 2);  f16* o1l = (f16*)allocB(PL * 2);
  f16* z0h = (f16*)allocB(PL * 2);  f16* z0l = (f16*)allocB(PL * 2);
  float* bbuf   = (float*)allocB(PL * 4);
  float* bfused = (float*)allocB((size_t)kG3N * 4);
  // weight planes
  f16* WfTh = (f16*)allocB(W1 * 3 * 2);  f16* WfTl = (f16*)allocB(W1 * 3 * 2);
  f16* WgBh = (f16*)allocB(W1 * 3 * 2);  f16* WgBl = (f16*)allocB(W1 * 3 * 2);
  f16* Wi2h = (f16*)allocB(W1 * 2);      f16* Wi2l = (f16*)allocB(W1 * 2);
  f16* Wi1Th = (f16*)allocB(W1 * 2);     f16* Wi1Tl = (f16*)allocB(W1 * 2);
  f16* Wo1Th = (f16*)allocB(W1 * 2 * 2); f16* Wo1Tl = (f16*)allocB(W1 * 2 * 2);
  f16* Wp1Th = (f16*)allocB(W1 * 2);     f16* Wp1Tl = (f16*)allocB(W1 * 2);
  f16* Wp2Th = (f16*)allocB(W1 * 2);     f16* Wp2Tl = (f16*)allocB(W1 * 2);
  f16* Wo2Th = (f16*)allocB(W1 * 2);     f16* Wo2Tl = (f16*)allocB(W1 * 2);
  int* cnt = (int*)allocB(256);

  // grid size: all blocks must be co-resident for the counter barrier.
  static int s_nb = 0;
  if (s_nb == 0) {
    int dev = 0;
    (void)hipGetDevice(&dev);
    int cu = 0;
    if (hipDeviceGetAttribute(&cu, hipDeviceAttributeMultiprocessorCount, dev) != hipSuccess || cu <= 0)
      cu = 256;
    int occ = 0;
    if (hipOccupancyMaxActiveBlocksPerMultiprocessor(&occ, k_scan, 256, 0) != hipSuccess || occ < 1)
      occ = 1;
    long nb = (long)occ * (long)cu;
    if (nb > 384) nb = 384;
    if (nb < 64) nb = 64;
    s_nb = (int)nb;
  }
  const int NB = s_nb;

  // ================= prologue =================
  k_convT<<<dim3(16, 48), 256, 0, stream>>>(Wg, 0, kG3N, 1024, WgTh, WgTl);
  k_convT<<<dim3(16, 48), 256, 0, stream>>>(Wg, 1024, kG3N, 1024, WgBh, WgBl);
  k_convT<<<dim3(16, 16), 256, 0, stream>>>(Wi1, 0, kN1, 1024, Wi1Th, Wi1Tl);
  k_convT<<<dim3(32, 16), 256, 0, stream>>>(Wo1, 0, kN1, 2048, Wo1Th, Wo1Tl);
  k_convT<<<dim3(16, 16), 256, 0, stream>>>(Wp1, 0, kN1, 1024, Wp1Th, Wp1Tl);
  k_convT<<<dim3(16, 16), 256, 0, stream>>>(Wp2, 0, kN1, 1024, Wp2Th, Wp2Tl);
  k_convT<<<dim3(16, 16), 256, 0, stream>>>(Wo2, 0, kN1, 1024, Wo2Th, Wo2Tl);
  k_conv<<<dim3(4096), 256, 0, stream>>>(Wi2, Wi2h, Wi2l);
  k_bfused<<<dim3(12), 256, 0, stream>>>(Wg, bi2, bfused);
  {  // Wfused = Wi2 @ WgTop (fp32 into overlay of Pg, plain layout)
    MJobs J{};
    J.j[0] = { Wi2h, Wi2l, nullptr, nullptr, WgTh, WgTl, Wfused_tmp, 1024, 1024, kG3N, 0, 1024, 48, 1, 0 };
    k_mgemm<<<dim3(8, 48, 1), 256, 0, stream>>>(J);
  }
  k_convT<<<dim3(16, 48), 256, 0, stream>>>(Wfused_tmp, 0, kG3N, 1024, WfTh, WfTl);
  // WgT region dead from here -> PD/PE reuse it
  k_setup<<<dim3(1024), 256, 0, stream>>>(b0, bbuf, bh, bl);
  k_conv<<<dim3(1024), 256, 0, stream>>>(z0, z0h, z0l);
  k_conv<<<dim3(1024), 256, 0, stream>>>(obs, o0h, o0l);    // obs[0]
  k_zero<<<dim3(1), 64, 0, stream>>>(cnt);
  {  // h1(t=0): z0 @ Wi1Top -> PD (plain layout), then finisher
    MJobs J{};
    J.j[0] = { z0h, z0l, nullptr, nullptr, Wi1Th, Wi1Tl, PD, 1024, 1024, kN1, 0, 1024, 16, 1, 0 };
    k_mgemm<<<dim3(2, 16, 1), 256, 0, stream>>>(J);
  }
  k_finish0<<<dim3(4, kB), 256, 0, stream>>>(PD, Wi1, bi1, acts, h1h, h1l);

  // ================= the scan: ONE persistent kernel =================
  ScanArgs A;
  A.obs = obs; A.acts = acts; A.unz = unz; A.out = out;
  A.lns = lns; A.lnb = lnb; A.bp1 = bp1; A.bo1 = bo1; A.bp2 = bp2; A.bo2 = bo2;
  A.Wi1 = Wi1; A.bi1 = bi1;
  A.Pg = Pg; A.PD = PD; A.PE = PE; A.bbuf = bbuf; A.bfused = bfused;
  A.WfTh = WfTh; A.WfTl = WfTl; A.WgBh = WgBh; A.WgBl = WgBl;
  A.Wp1Th = Wp1Th; A.Wp1Tl = Wp1Tl; A.Wo1Th = Wo1Th; A.Wo1Tl = Wo1Tl;
  A.Wp2Th = Wp2Th; A.Wp2Tl = Wp2Tl; A.Wo2Th = Wo2Th; A.Wo2Tl = Wo2Tl;
  A.h1h = h1h; A.h1l = h1l; A.bh = bh; A.bl = bl;
  A.hph = hph; A.hpl = hpl; A.hoh = hoh; A.hol = hol;
  A.o0h = o0h; A.o0l = o0l; A.o1h = o1h; A.o1l = o1l;
  A.cnt = cnt; A.NB = NB;
  k_scan<<<dim3(NB), dim3(256), 0, stream>>>(A);
}

// Round 4
// 10577.631 us; speedup vs baseline: 1.7997x; 1.1353x over previous
//
#include <hip/hip_runtime.h>
#include <math.h>

// DreamBeliefTracker — round 8: persistent scan, pipelined GEMM + XCD barrier.
//  * Round-7 PASSED (absmax 0.0) at 12.5 ms: fence-free MALL coherence works.
//    Costs measured: latency-chained K-loops (drain-all per iter) + flat
//    384-block barrier contention + 2x weight fetch (split-K twins on
//    different XCDs).
//  * Round-8 (same coherence protocol, bit-exact math):
//    1) ring-3 LDS + counted s_waitcnt vmcnt(6) + raw s_barrier: 2 DMA
//       batches in flight across K-iters (T3/T4).
//    2) hierarchical barrier: per-XCD arrive counters (XCC_ID self-id;
//       any id value is correctness-safe), 8 leaders on root, per-XCD go.
//    3) task permutation: split-K twins sharing a W panel -> same XCD
//       (blockIdx%8 heuristic, perf-only).

typedef _Float16 f16;
typedef _Float16 f16x8 __attribute__((ext_vector_type(8)));
typedef float f32x4 __attribute__((ext_vector_type(4)));

constexpr int kB = 256, kN1 = 1024, kG3N = 3072, kActD = 6, kT = 64;
constexpr float kLoScale = 4096.f;
constexpr float kLoInv = 1.f / 4096.f;

// ---- coherent (cross-XCD via MALL) accessors — no fences, no L2 inv ----
__device__ __forceinline__ float lda_sc(const float* p) {
  return __hip_atomic_load(p, __ATOMIC_RELAXED, __HIP_MEMORY_SCOPE_AGENT);
}
__device__ __forceinline__ void stg_sc(float* p, float v) {
  __hip_atomic_store(p, v, __ATOMIC_RELAXED, __HIP_MEMORY_SCOPE_AGENT);
}
__device__ __forceinline__ void sth_sc(f16* p, f16 v) {
  __hip_atomic_store((unsigned short*)p, __builtin_bit_cast(unsigned short, v),
                     __ATOMIC_RELAXED, __HIP_MEMORY_SCOPE_AGENT);
}
__device__ __forceinline__ int aadd(int* p, int v) {
  return __hip_atomic_fetch_add(p, v, __ATOMIC_RELAXED, __HIP_MEMORY_SCOPE_AGENT);
}
__device__ __forceinline__ int ald(int* p) {
  return __hip_atomic_load(p, __ATOMIC_RELAXED, __HIP_MEMORY_SCOPE_AGENT);
}

__device__ __forceinline__ void wr_planes(f16* hi, f16* lo, size_t i, float x) {
  f16 h = (f16)x;
  hi[i] = h;
  lo[i] = (f16)((x - (float)h) * kLoScale);
}
__device__ __forceinline__ void wr_planes_sc(f16* hi, f16* lo, size_t i, float x) {
  f16 h = (f16)x;
  sth_sc(hi + i, h);
  sth_sc(lo + i, (f16)((x - (float)h) * kLoScale));
}

// weights: normal cacheable DMA.  activations: sc0|sc1 (aux=1|16=17) DMA.
__device__ __forceinline__ void glds16w(const f16* g, f16* l) {
  __builtin_amdgcn_global_load_lds(
      (const __attribute__((address_space(1))) unsigned int*)g,
      (__attribute__((address_space(3))) unsigned int*)l, 16, 0, 0);
}
__device__ __forceinline__ void glds16a(const f16* g, f16* l) {
  __builtin_amdgcn_global_load_lds(
      (const __attribute__((address_space(1))) unsigned int*)g,
      (__attribute__((address_space(3))) unsigned int*)l, 16, 0, 17);
}

// ---------------------------------------------------------- shared LDS union
struct GemmLDS { f16 As[3][2][8][64][8]; f16 Ws[3][2][4][64][8]; };  // 72 KB
struct GruLDS  { float sh[kG3N]; float red[8]; };                    // 12.3 KB
struct SmpLDS  { float skl[32]; int sidx[32]; };                     // 256 B
union ScanLDS  { GemmLDS g; GruLDS r; SmpLDS s; };

// ------------------------------------------------------------- MFMA GEMM ----
// 256 threads (4 waves, 2m x 2n), tile 128x64, BK=32. Ring-3 LDS with counted
// vmcnt: per wave 6 DMAs/batch; 2 batches stay in flight across K-iters.
// A planes sc0sc1 DMA; W planes plain. Output sc0sc1 at 64B granule.
__device__ void dev_mgemm(GemmLDS& L, const f16* A1h, const f16* A1l,
                          const f16* A2h, const f16* A2l,
                          const f16* Wph, const f16* Wpl, float* outF,
                          int cols1, int K, int Nout, int k0, int klen,
                          int bx, int by, int pstride, int pidx) {
  const int m0 = bx * 128, n0 = by * 64;
  const int tid = threadIdx.x, wave = tid >> 6, lane = tid & 63;
  const int rlo = lane & 15, khi = (lane >> 4) * 8;
  const int wmf = (wave & 1) * 4, wnf = (wave >> 1) * 2;

  f32x4 acc1[4][2], acc2[4][2];
#pragma unroll
  for (int i = 0; i < 4; ++i)
#pragma unroll
    for (int j = 0; j < 2; ++j)
#pragma unroll
      for (int r = 0; r < 4; ++r) { acc1[i][j][r] = 0.f; acc2[i][j][r] = 0.f; }

  auto issueTile = [&](int it, int buf) {   // 6 DMAs per wave
    const int kg = k0 + it * 32;
    const f16 *h, *l; int rs, cb;
    if (kg < cols1) { h = A1h; l = A1l; rs = cols1; cb = kg; }
    else { h = A2h; l = A2l; rs = K - cols1; cb = kg - cols1; }
#pragma unroll
    for (int i = 0; i < 2; ++i) {
      const int mf = wave * 2 + i;
      const size_t go = (size_t)(m0 + mf * 16 + rlo) * rs + cb + khi;
      glds16a(h + go, &L.As[buf][0][mf][0][0]);
      glds16a(l + go, &L.As[buf][1][mf][0][0]);
    }
    const size_t wo = (size_t)(n0 + wave * 16 + rlo) * K + kg + khi;
    glds16w(Wph + wo, &L.Ws[buf][0][wave][0][0]);
    glds16w(Wpl + wo, &L.Ws[buf][1][wave][0][0]);
  };

  const int niter = klen >> 5;              // always >= 16 here
  issueTile(0, 0);
  if (niter > 1) issueTile(1, 1);
#pragma unroll 1
  for (int it = 0; it < niter; ++it) {
    const int buf = it % 3;
    if (it + 1 < niter) {                   // batch `it` done; batch it+1 stays
      asm volatile("s_waitcnt vmcnt(6)" ::: "memory");
    } else {
      asm volatile("s_waitcnt vmcnt(0)" ::: "memory");
    }
    __builtin_amdgcn_s_barrier();           // all waves: batch it in LDS,
    asm volatile("" ::: "memory");          //   all done computing it-1
    if (it + 2 < niter) issueTile(it + 2, (it + 2) % 3);  // overwrites buf it-1
    f16x8 Af[4][2], Wf[2][2];
#pragma unroll
    for (int mf = 0; mf < 4; ++mf) {
      Af[mf][0] = *(const f16x8*)&L.As[buf][0][wmf + mf][lane][0];
      Af[mf][1] = *(const f16x8*)&L.As[buf][1][wmf + mf][lane][0];
    }
#pragma unroll
    for (int nf = 0; nf < 2; ++nf) {
      Wf[nf][0] = *(const f16x8*)&L.Ws[buf][0][wnf + nf][lane][0];
      Wf[nf][1] = *(const f16x8*)&L.Ws[buf][1][wnf + nf][lane][0];
    }
#pragma unroll
    for (int mf = 0; mf < 4; ++mf)
#pragma unroll
      for (int nf = 0; nf < 2; ++nf) {
        acc1[mf][nf] = __builtin_amdgcn_mfma_f32_16x16x32_f16(Af[mf][0], Wf[nf][0], acc1[mf][nf], 0, 0, 0);
        acc2[mf][nf] = __builtin_amdgcn_mfma_f32_16x16x32_f16(Af[mf][0], Wf[nf][1], acc2[mf][nf], 0, 0, 0);
        acc2[mf][nf] = __builtin_amdgcn_mfma_f32_16x16x32_f16(Af[mf][1], Wf[nf][0], acc2[mf][nf], 0, 0, 0);
      }
  }
  __syncthreads();                          // protect LDS reuse by next task
  const int orow = m0 + (wave & 1) * 64, ocol = n0 + (wave >> 1) * 32;
#pragma unroll
  for (int mf = 0; mf < 4; ++mf)
#pragma unroll
    for (int nf = 0; nf < 2; ++nf)
#pragma unroll
      for (int r = 0; r < 4; ++r) {
        const int row = orow + mf * 16 + (lane >> 4) * 4 + r;
        const int col = ocol + nf * 16 + rlo;
        const int o = row * Nout + col;
        float* dst = outF + ((size_t)(o >> 4) * pstride + pidx) * 16 + (o & 15);
        stg_sc(dst, acc1[mf][nf][r] + acc2[mf][nf][r] * kLoInv);
      }
}

// --------- LayerNorm + GRU (sums 4 gate partials) + next-step obs staging ---
__device__ void dev_gru(GruLDS& G, int b, const float* Pg, const float* bfused,
                        const float* lns, const float* lnb, float* bbuf,
                        f16* bh, f16* bl, const float* obs_next,
                        f16* oh, f16* ol, int do_obs) {
  const int tid = threadIdx.x;
  float v[12];
  float sum = 0.f, sq = 0.f;
#pragma unroll
  for (int i = 0; i < 12; ++i) {
    const int j = tid + i * 256;
    const size_t o = (size_t)b * kG3N + j;
    const float* base = Pg + ((o >> 4) * 4) * 16 + (o & 15);
    const float q0 = lda_sc(base),      q1 = lda_sc(base + 16);
    const float q2 = lda_sc(base + 32), q3 = lda_sc(base + 48);
    const float s = (((q0 + q1) + q2) + q3) + bfused[j];
    v[i] = s; sum += s; sq += s * s;
  }
  if (do_obs) {
#pragma unroll
    for (int i = 0; i < 4; ++i) {
      const int j = tid + i * 256;
      wr_planes_sc(oh, ol, (size_t)b * kN1 + j, obs_next[(size_t)b * kN1 + j]);
    }
  }
  for (int m = 1; m <= 32; m <<= 1) { sum += __shfl_xor(sum, m); sq += __shfl_xor(sq, m); }
  if ((tid & 63) == 0) { G.red[(tid >> 6) * 2] = sum; G.red[(tid >> 6) * 2 + 1] = sq; }
  __syncthreads();
  float ts = 0.f, tq = 0.f;
  for (int w = 0; w < 4; ++w) { ts += G.red[w * 2]; tq += G.red[w * 2 + 1]; }
  const float mu   = ts * (1.f / kG3N);
  const float var  = tq * (1.f / kG3N) - mu * mu;
  const float rinv = 1.f / sqrtf(var + 1e-3f);
#pragma unroll
  for (int i = 0; i < 12; ++i) {
    const int j = tid + i * 256;
    G.sh[j] = (v[i] - mu) * rinv * lns[j] + lnb[j];
  }
  __syncthreads();
#pragma unroll
  for (int i = 0; i < 4; ++i) {
    const int j = tid + i * 256;
    const float r = G.sh[j], c = G.sh[kN1 + j], u = G.sh[2 * kN1 + j];
    const float reset = 1.f / (1.f + expf(-r));
    const float cand  = tanhf(reset * c);
    const float upd   = 1.f / (1.f + expf(-(u - 1.f)));   // UPDATE_BIAS = -1
    const size_t o = (size_t)b * kN1 + j;
    const float bn = upd * cand + (1.f - upd) * bbuf[o];
    bbuf[o] = bn;                 // same persistent block every step: plain ok
    wr_planes_sc(bh, bl, o, bn);
  }
}

// -- softmax/unimix/KL + Gumbel argmax + fused h1 gather (256-thr version) ---
__device__ void dev_sample(SmpLDS& S, int b, const float* PE,
                           const float* bp2, const float* bo2,
                           const float* unz_t, float* loss_t,
                           const float* Wi1, const float* bi1,
                           const float* act_next, f16* h1h, f16* h1l,
                           int do_gather) {
  const int tid = threadIdx.x;
  __syncthreads();
#pragma unroll
  for (int c = 0; c < 4; ++c) {
    const int j = c * 256 + tid;
    const int o = b * kN1 + j;
    const float* base = PE + ((size_t)(o >> 4) * 4) * 16 + (o & 15);
    const float e0 = lda_sc(base),      e1 = lda_sc(base + 16);
    const float e2 = lda_sc(base + 32), e3 = lda_sc(base + 48);
    float lp = e0 + e1 + bp2[j];
    float lo = e2 + e3 + bo2[j];
    lp = fminf(fmaxf(lp, -20.f), 20.f);
    lo = fminf(fmaxf(lo, -20.f), 20.f);
    float mp = lp, mo = lo;
    for (int m = 1; m <= 16; m <<= 1) { mp = fmaxf(mp, __shfl_xor(mp, m)); mo = fmaxf(mo, __shfl_xor(mo, m)); }
    const float ep = expf(lp - mp), eo = expf(lo - mo);
    float sp = ep, so = eo;
    for (int m = 1; m <= 16; m <<= 1) { sp += __shfl_xor(sp, m); so += __shfl_xor(so, m); }
    const float pp = (ep / sp) * 0.99f + (0.01f / 32.f);
    const float po = (eo / so) * 0.99f + (0.01f / 32.f);
    float kt = po * (logf(po + 1e-8f) - logf(pp + 1e-8f));
    for (int m = 1; m <= 16; m <<= 1) kt += __shfl_xor(kt, m);
    const float u = unz_t[o];
    const float g = -logf(-logf(u + 1e-6f) + 1e-6f);
    float vv = logf(fmaxf(po, 1e-6f)) + g;
    int ii = j & 31;
    for (int m = 1; m <= 16; m <<= 1) {
      const float vo = __shfl_xor(vv, m);
      const int   io = __shfl_xor(ii, m);
      if (vo > vv || (vo == vv && io < ii)) { vv = vo; ii = io; }   // first-max ties
    }
    if ((tid & 31) == 0) { S.skl[j >> 5] = kt; S.sidx[j >> 5] = ii; }
  }
  __syncthreads();
  if (tid == 0) {
    float kl = 0.f;
    for (int gg = 0; gg < 32; ++gg) kl += S.skl[gg];
    const float dl = fmaxf(kl, 0.1f);
    loss_t[b] = 1.0f * dl + 0.1f * dl;
  }
  if (do_gather) {
#pragma unroll
    for (int c = 0; c < 4; ++c) {
      const int j = c * 256 + tid;
      float s = bi1[j];
#pragma unroll
      for (int gg = 0; gg < 32; ++gg)
        s += Wi1[(size_t)(gg * 32 + S.sidx[gg]) * kN1 + j];
#pragma unroll
      for (int k = 0; k < kActD; ++k)
        s += act_next[b * kActD + k] * Wi1[(size_t)(kN1 + k) * kN1 + j];
      s = s * (1.f / (1.f + expf(-s)));
      wr_planes_sc(h1h, h1l, (size_t)b * kN1 + j, s);
    }
  }
}

// -------------------------------------------------------- persistent scan ---
// Counter layout (64B-strided ints): [x*16]=reg pool x<8; [8*16]=reg root;
// [(9+x)*16]=arrive x; [17*16]=root; [(18+x)*16]=go x.  416 ints total.
struct ScanArgs {
  const float *obs, *acts, *unz;
  float* out;
  const float *lns, *lnb, *bp1, *bo1, *bp2, *bo2, *Wi1, *bi1;
  float *Pg, *PD, *PE, *bbuf, *bfused;
  const f16 *WfTh, *WfTl, *WgBh, *WgBl;
  const f16 *Wp1Th, *Wp1Tl, *Wo1Th, *Wo1Tl, *Wp2Th, *Wp2Tl, *Wo2Th, *Wo2Tl;
  f16 *h1h, *h1l, *bh, *bl, *hph, *hpl, *hoh, *hol, *o0h, *o0l, *o1h, *o1l;
  int* cnt;
  int NB;
};

// Hierarchical fence-free barrier (round-7 coherence model):
// every wave drains its sc1 stores (vmcnt0) -> per-XCD arrive -> pool closer
// aggregates to root -> closers wait root -> per-XCD go broadcast.
__device__ __forceinline__ void gsync2(int* cnt, int xcd, int psize, int NB, int gen) {
  asm volatile("s_waitcnt vmcnt(0)" ::: "memory");
  __syncthreads();
  if (threadIdx.x == 0) {
    int* arr  = cnt + (9 + xcd) * 16;
    int* root = cnt + 17 * 16;
    int* go   = cnt + (18 + xcd) * 16;
    const int a = aadd(arr, 1) + 1;
    if (a == gen * psize) {                 // unique closer for this XCD
      const int r = aadd(root, psize) + psize;
      if (r < gen * NB) {
        int guard = 0;
        while (ald(root) < gen * NB) {
          __builtin_amdgcn_s_sleep(2);
          if (++guard > (1 << 20)) break;
        }
      }
      __hip_atomic_store(go, gen, __ATOMIC_RELAXED, __HIP_MEMORY_SCOPE_AGENT);
    } else {
      int guard = 0;
      while (ald(go) < gen) {
        __builtin_amdgcn_s_sleep(2);
        if (++guard > (1 << 20)) break;
      }
    }
  }
  __syncthreads();
}

// split-K twin (bx=0/1 sharing one W panel) -> same XCD class (perf heuristic)
__device__ __forceinline__ int permW(int B2, int pairsPerCls) {
  const int cls = B2 & 7, k = B2 >> 3;
  return ((cls * pairsPerCls + (k >> 1)) << 1) | (k & 1);
}

__global__ __launch_bounds__(256, 2) void k_scan(ScanArgs a) {
  __shared__ ScanLDS L;
  __shared__ int sXcd, sPsize;
  const int NB = a.NB;
  int* cnt = a.cnt;

  // ---- registration: self-identify physical XCD, size the pools ----
  if (threadIdx.x == 0) {
    int x;
    asm volatile("s_getreg_b32 %0, hwreg(20, 0, 4)" : "=s"(x));  // HW_REG_XCC_ID
    x &= 7;
    aadd(cnt + x * 16, 1);
    asm volatile("s_waitcnt vmcnt(0)" ::: "memory");  // pool inc lands first
    const int r = aadd(cnt + 8 * 16, 1) + 1;
    if (r < NB) {
      int guard = 0;
      while (ald(cnt + 8 * 16) < NB) {
        __builtin_amdgcn_s_sleep(2);
        if (++guard > (1 << 20)) break;
      }
    }
    sXcd = x;
    sPsize = ald(cnt + x * 16);
  }
  __syncthreads();
  const int xcd = sXcd, psize = sPsize;
  int syncno = 0;

#pragma unroll 1
  for (int t = 0; t < kT; ++t) {
    const f16* oth = (t & 1) ? a.o1h : a.o0h;
    const f16* otl = (t & 1) ? a.o1l : a.o0l;
    f16* onh = (t & 1) ? a.o0h : a.o1h;
    f16* onl = (t & 1) ? a.o0l : a.o1l;

    // phase 1: gates — parts 0/1 = h1 @ WfT (splitK2); parts 2/3 = b @ WgB
#pragma unroll 1
    for (int B2 = blockIdx.x; B2 < 384; B2 += NB) {
      const int task = permW(B2, 24);
      const int j = task / 96, r = task % 96, bx = r & 1, by = r >> 1;
      const bool top = (j < 2);
      dev_mgemm(L.g, top ? a.h1h : a.bh, top ? a.h1l : a.bl, nullptr, nullptr,
                top ? a.WfTh : a.WgBh, top ? a.WfTl : a.WgBl,
                a.Pg, 1024, 1024, kG3N, (j & 1) * 512, 512, bx, by, 4, j);
    }
    gsync2(cnt, xcd, psize, NB, ++syncno);

    // phase 2: LN + GRU + stage next-step obs planes
#pragma unroll 1
    for (int b = blockIdx.x; b < kB; b += NB)
      dev_gru(L.r, b, a.Pg, a.bfused, a.lns, a.lnb, a.bbuf, a.bh, a.bl,
              a.obs + (size_t)(t + 1) * kB * kN1, onh, onl, (t < kT - 1) ? 1 : 0);
    gsync2(cnt, xcd, psize, NB, ++syncno);

    // phase 3: D — parts 0/1 = b @ Wp1T (splitK2); parts 2..5 = [obs,b] @ Wo1T
#pragma unroll 1
    for (int B2 = blockIdx.x; B2 < 192; B2 += NB) {
      const int task = permW(B2, 12);
      const int j = task >> 5, r = task & 31, bx = r & 1, by = r >> 1;
      const f16 *Ah, *Al, *A2h = nullptr, *A2l = nullptr, *Wh, *Wl;
      int K, k0;
      if (j < 2) { Ah = a.bh; Al = a.bl; Wh = a.Wp1Th; Wl = a.Wp1Tl; K = 1024; k0 = j * 512; }
      else { Ah = oth; Al = otl; A2h = a.bh; A2l = a.bl; Wh = a.Wo1Th; Wl = a.Wo1Tl; K = 2048; k0 = (j - 2) * 512; }
      dev_mgemm(L.g, Ah, Al, A2h, A2l, Wh, Wl,
                a.PD, 1024, K, kN1, k0, 512, bx, by, 6, j);
    }
    gsync2(cnt, xcd, psize, NB, ++syncno);

    // phase 4: combine — hp = silu(p0+p1+bp1); ho = silu(p2+p3+p4+p5+bo1)
#pragma unroll 1
    for (int idx = blockIdx.x; idx < 1024; idx += NB) {
      const int i = idx * 256 + (int)threadIdx.x;
      const float* base = a.PD + ((size_t)(i >> 4) * 6) * 16 + (i & 15);
      const float p0 = lda_sc(base),      p1 = lda_sc(base + 16);
      const float p2 = lda_sc(base + 32), p3 = lda_sc(base + 48);
      const float p4 = lda_sc(base + 64), p5 = lda_sc(base + 80);
      float sp = (p0 + p1) + a.bp1[i & (kN1 - 1)];
      sp = sp * (1.f / (1.f + expf(-sp)));
      wr_planes_sc(a.hph, a.hpl, i, sp);
      float so = (((p2 + p3) + p4) + p5) + a.bo1[i & (kN1 - 1)];
      so = so * (1.f / (1.f + expf(-so)));
      wr_planes_sc(a.hoh, a.hol, i, so);
    }
    gsync2(cnt, xcd, psize, NB, ++syncno);

    // phase 5: E — parts 0/1 = hp @ Wp2T; parts 2/3 = ho @ Wo2T (splitK2 each)
#pragma unroll 1
    for (int B2 = blockIdx.x; B2 < 128; B2 += NB) {
      const int task = permW(B2, 8);
      const int j = task >> 5, r = task & 31, bx = r & 1, by = r >> 1;
      const bool pr = (j < 2);
      dev_mgemm(L.g, pr ? a.hph : a.hoh, pr ? a.hpl : a.hol, nullptr, nullptr,
                pr ? a.Wp2Th : a.Wo2Th, pr ? a.Wp2Tl : a.Wo2Tl,
                a.PE, 1024, 1024, kN1, (j & 1) * 512, 512, bx, by, 4, j);
    }
    gsync2(cnt, xcd, psize, NB, ++syncno);

    // phase 6: sample + KL loss + next-step h1 gather
#pragma unroll 1
    for (int b = blockIdx.x; b < kB; b += NB)
      dev_sample(L.s, b, a.PE, a.bp2, a.bo2, a.unz + (size_t)t * kB * kN1,
                 a.out + (size_t)t * kB, a.Wi1, a.bi1,
                 a.acts + (size_t)(t + 1) * kB * kActD, a.h1h, a.h1l,
                 (t < kT - 1) ? 1 : 0);
    gsync2(cnt, xcd, psize, NB, ++syncno);
  }
}

// ------------------------------------------------------------- prologue -----
struct MJob {
  const f16 *A1h, *A1l, *A2h, *A2l;
  const f16 *Wph, *Wpl;
  float* outF;
  int cols1, K, Nout, k0, klen, ny, pstride, pidx;
};
struct MJobs { MJob j[6]; };

__global__ __launch_bounds__(256, 2) void k_mgemm(MJobs js) {
  const MJob jb = js.j[blockIdx.z];
  if ((int)blockIdx.y >= jb.ny) return;
  __shared__ GemmLDS L;
  dev_mgemm(L, jb.A1h, jb.A1l, jb.A2h, jb.A2l, jb.Wph, jb.Wpl, jb.outF,
            jb.cols1, jb.K, jb.Nout, jb.k0, jb.klen, blockIdx.x, blockIdx.y,
            jb.pstride, jb.pidx);
}

__global__ __launch_bounds__(256) void k_conv(const float* src, f16* dh, f16* dl) {
  const size_t i = (size_t)blockIdx.x * 256 + threadIdx.x;
  wr_planes(dh, dl, i, src[i]);
}

__global__ __launch_bounds__(256) void k_convT(const float* src, int rowoff, int srcN,
                                               int K, f16* dh, f16* dl) {
  __shared__ float T[64][65];
  const int k0 = blockIdx.x * 64, n0 = blockIdx.y * 64;
  const int tx = threadIdx.x & 63, ty = threadIdx.x >> 6;
#pragma unroll 4
  for (int i = 0; i < 16; ++i) {
    const int k = ty * 16 + i;
    T[k][tx] = src[(size_t)(rowoff + k0 + k) * srcN + n0 + tx];
  }
  __syncthreads();
#pragma unroll 4
  for (int i = 0; i < 16; ++i) {
    const int n = ty * 16 + i;
    const float x = T[tx][n];
    const size_t o = (size_t)(n0 + n) * K + k0 + tx;
    f16 h = (f16)x;
    dh[o] = h;
    dl[o] = (f16)((x - (float)h) * kLoScale);
  }
}

__global__ __launch_bounds__(256) void k_bfused(const float* Wg, const float* bi2, float* bf) {
  const int n = blockIdx.x * 256 + threadIdx.x;
  float s = 0.f;
  for (int j = 0; j < 1024; ++j) s += bi2[j] * Wg[(size_t)j * kG3N + n];
  bf[n] = s;
}

__global__ __launch_bounds__(256) void k_setup(const float* b0, float* bbuf, f16* bh, f16* bl) {
  const size_t i = (size_t)blockIdx.x * 256 + threadIdx.x;
  const float b = b0[i];
  bbuf[i] = b;
  wr_planes(bh, bl, i, b);
}

__global__ void k_zero(int* p) {
  const int i = blockIdx.x * 256 + threadIdx.x;
  if (i < 512) p[i] = 0;
}

__global__ __launch_bounds__(256) void k_finish0(const float* P, const float* Wi1,
    const float* bi1, const float* act0, f16* h1h, f16* h1l) {
  const int b = blockIdx.y;
  const int j = blockIdx.x * 256 + threadIdx.x;
  __shared__ float sact[kActD];
  if (threadIdx.x < kActD) sact[threadIdx.x] = act0[b * kActD + threadIdx.x];
  __syncthreads();
  float s = P[(size_t)b * kN1 + j] + bi1[j];
#pragma unroll
  for (int k = 0; k < kActD; ++k) s += sact[k] * Wi1[(size_t)(kN1 + k) * kN1 + j];
  s = s * (1.f / (1.f + expf(-s)));
  wr_planes(h1h, h1l, (size_t)b * kN1 + j, s);
}

// ---------------------------------------------------------------------------
extern "C" void kernel_launch(void* const* d_in, const int* in_sizes, int n_in,
                              void* d_out, int out_size, void* d_ws, size_t ws_size,
                              hipStream_t stream) {
  const float* b0   = (const float*)d_in[0];
  const float* z0   = (const float*)d_in[1];
  const float* acts = (const float*)d_in[2];
  const float* obs  = (const float*)d_in[3];
  const float* unz  = (const float*)d_in[4];
  const float* Wi1  = (const float*)d_in[5];
  const float* bi1  = (const float*)d_in[6];
  const float* Wi2  = (const float*)d_in[7];
  const float* bi2  = (const float*)d_in[8];
  const float* Wg   = (const float*)d_in[9];
  const float* lns  = (const float*)d_in[10];
  const float* lnb  = (const float*)d_in[11];
  const float* Wo1  = (const float*)d_in[12];
  const float* bo1  = (const float*)d_in[13];
  const float* Wo2  = (const float*)d_in[14];
  const float* bo2  = (const float*)d_in[15];
  const float* Wp1  = (const float*)d_in[16];
  const float* bp1  = (const float*)d_in[17];
  const float* Wp2  = (const float*)d_in[18];
  const float* bp2  = (const float*)d_in[19];
  float* out = (float*)d_out;

  char* wsb = (char*)d_ws;
  size_t off = 0;
  auto allocB = [&](size_t bytes) { char* p = wsb + off; off += (bytes + 255) & ~(size_t)255; return p; };
  const size_t PL = (size_t)kB * kN1;
  const size_t S3 = (size_t)kB * kG3N;
  const size_t W1 = (size_t)kN1 * kN1;

  // region A: gate partials (4 x 256x3072 fp32 = 12 MB) — overlays Wfused_tmp
  float* Pg = (float*)allocB(4 * S3 * 4);
  float* Wfused_tmp = Pg;
  // region B: WgT planes (prologue-only, 12.6 MB) — overlays PD (6 MB) + PE (4 MB)
  f16* WgTh = (f16*)allocB(W1 * 3 * 2);
  f16* WgTl = (f16*)allocB(W1 * 3 * 2);
  float* PD = (float*)WgTh;
  float* PE = (float*)WgTl;
  // persistent planes / state
  f16* h1h = (f16*)allocB(PL * 2);  f16* h1l = (f16*)allocB(PL * 2);
  f16* bh  = (f16*)allocB(PL * 2);  f16* bl  = (f16*)allocB(PL * 2);
  f16* hph = (f16*)allocB(PL * 2);  f16* hpl = (f16*)allocB(PL * 2);
  f16* hoh = (f16*)allocB(PL * 2);  f16* hol = (f16*)allocB(PL * 2);
  f16* o0h = (f16*)allocB(PL * 2);  f16* o0l = (f16*)allocB(PL * 2);
  f16* o1h = (f16*)allocB(PL * 2);  f16* o1l = (f16*)allocB(PL * 2);
  f16* z0h = (f16*)allocB(PL * 2);  f16* z0l = (f16*)allocB(PL * 2);
  float* bbuf   = (float*)allocB(PL * 4);
  float* bfused = (float*)allocB((size_t)kG3N * 4);
  // weight planes
  f16* WfTh = (f16*)allocB(W1 * 3 * 2);  f16* WfTl = (f16*)allocB(W1 * 3 * 2);
  f16* WgBh = (f16*)allocB(W1 * 3 * 2);  f16* WgBl = (f16*)allocB(W1 * 3 * 2);
  f16* Wi2h = (f16*)allocB(W1 * 2);      f16* Wi2l = (f16*)allocB(W1 * 2);
  f16* Wi1Th = (f16*)allocB(W1 * 2);     f16* Wi1Tl = (f16*)allocB(W1 * 2);
  f16* Wo1Th = (f16*)allocB(W1 * 2 * 2); f16* Wo1Tl = (f16*)allocB(W1 * 2 * 2);
  f16* Wp1Th = (f16*)allocB(W1 * 2);     f16* Wp1Tl = (f16*)allocB(W1 * 2);
  f16* Wp2Th = (f16*)allocB(W1 * 2);     f16* Wp2Tl = (f16*)allocB(W1 * 2);
  f16* Wo2Th = (f16*)allocB(W1 * 2);     f16* Wo2Tl = (f16*)allocB(W1 * 2);
  int* cnt = (int*)allocB(4096);

  // grid size: all blocks must be co-resident for the counter barrier.
  static int s_nb = 0;
  if (s_nb == 0) {
    int dev = 0;
    (void)hipGetDevice(&dev);
    int cu = 0;
    if (hipDeviceGetAttribute(&cu, hipDeviceAttributeMultiprocessorCount, dev) != hipSuccess || cu <= 0)
      cu = 256;
    int occ = 0;
    if (hipOccupancyMaxActiveBlocksPerMultiprocessor(&occ, k_scan, 256, 0) != hipSuccess || occ < 1)
      occ = 1;
    long nb = (long)occ * (long)cu;
    if (nb > 384) nb = 384;
    if (nb < 64) nb = 64;
    s_nb = (int)nb;
  }
  const int NB = s_nb;

  // ================= prologue =================
  k_convT<<<dim3(16, 48), 256, 0, stream>>>(Wg, 0, kG3N, 1024, WgTh, WgTl);
  k_convT<<<dim3(16, 48), 256, 0, stream>>>(Wg, 1024, kG3N, 1024, WgBh, WgBl);
  k_convT<<<dim3(16, 16), 256, 0, stream>>>(Wi1, 0, kN1, 1024, Wi1Th, Wi1Tl);
  k_convT<<<dim3(32, 16), 256, 0, stream>>>(Wo1, 0, kN1, 2048, Wo1Th, Wo1Tl);
  k_convT<<<dim3(16, 16), 256, 0, stream>>>(Wp1, 0, kN1, 1024, Wp1Th, Wp1Tl);
  k_convT<<<dim3(16, 16), 256, 0, stream>>>(Wp2, 0, kN1, 1024, Wp2Th, Wp2Tl);
  k_convT<<<dim3(16, 16), 256, 0, stream>>>(Wo2, 0, kN1, 1024, Wo2Th, Wo2Tl);
  k_conv<<<dim3(4096), 256, 0, stream>>>(Wi2, Wi2h, Wi2l);
  k_bfused<<<dim3(12), 256, 0, stream>>>(Wg, bi2, bfused);
  {  // Wfused = Wi2 @ WgTop (fp32 into overlay of Pg, plain layout)
    MJobs J{};
    J.j[0] = { Wi2h, Wi2l, nullptr, nullptr, WgTh, WgTl, Wfused_tmp, 1024, 1024, kG3N, 0, 1024, 48, 1, 0 };
    k_mgemm<<<dim3(8, 48, 1), 256, 0, stream>>>(J);
  }
  k_convT<<<dim3(16, 48), 256, 0, stream>>>(Wfused_tmp, 0, kG3N, 1024, WfTh, WfTl);
  // WgT region dead from here -> PD/PE reuse it
  k_setup<<<dim3(1024), 256, 0, stream>>>(b0, bbuf, bh, bl);
  k_conv<<<dim3(1024), 256, 0, stream>>>(z0, z0h, z0l);
  k_conv<<<dim3(1024), 256, 0, stream>>>(obs, o0h, o0l);    // obs[0]
  k_zero<<<dim3(2), 256, 0, stream>>>(cnt);
  {  // h1(t=0): z0 @ Wi1Top -> PD (plain layout), then finisher
    MJobs J{};
    J.j[0] = { z0h, z0l, nullptr, nullptr, Wi1Th, Wi1Tl, PD, 1024, 1024, kN1, 0, 1024, 16, 1, 0 };
    k_mgemm<<<dim3(2, 16, 1), 256, 0, stream>>>(J);
  }
  k_finish0<<<dim3(4, kB), 256, 0, stream>>>(PD, Wi1, bi1, acts, h1h, h1l);

  // ================= the scan: ONE persistent kernel =================
  ScanArgs A;
  A.obs = obs; A.acts = acts; A.unz = unz; A.out = out;
  A.lns = lns; A.lnb = lnb; A.bp1 = bp1; A.bo1 = bo1; A.bp2 = bp2; A.bo2 = bo2;
  A.Wi1 = Wi1; A.bi1 = bi1;
  A.Pg = Pg; A.PD = PD; A.PE = PE; A.bbuf = bbuf; A.bfused = bfused;
  A.WfTh = WfTh; A.WfTl = WfTl; A.WgBh = WgBh; A.WgBl = WgBl;
  A.Wp1Th = Wp1Th; A.Wp1Tl = Wp1Tl; A.Wo1Th = Wo1Th; A.Wo1Tl = Wo1Tl;
  A.Wp2Th = Wp2Th; A.Wp2Tl = Wp2Tl; A.Wo2Th = Wo2Th; A.Wo2Tl = Wo2Tl;
  A.h1h = h1h; A.h1l = h1l; A.bh = bh; A.bl = bl;
  A.hph = hph; A.hpl = hpl; A.hoh = hoh; A.hol = hol;
  A.o0h = o0h; A.o0l = o0l; A.o1h = o1h; A.o1l = o1l;
  A.cnt = cnt; A.NB = NB;
  k_scan<<<dim3(NB), dim3(256), 0, stream>>>(A);
}

// Round 5
// 6307.191 us; speedup vs baseline: 3.0183x; 1.6771x over previous
//
#include <hip/hip_runtime.h>
#include <math.h>

// DreamBeliefTracker — round 9: 3-launch hybrid (L2-coherent operands via
// launch boundaries + rounds-7/8-verified sc/MALL protocol inside a launch).
//  * Persistent kernel (rounds 5-8) proved the sc coherence protocol but pays
//    ~230 MB/step of uncacheable A-plane re-streaming (L2 bypass x by-reuse) —
//    structurally slower than launches (A/W L2-cached across boundaries).
//  * Round-9: per step, 3 launches:
//      A) k_gates_gru : 384 blocks — gate GEMM tasks (sc partials) -> flag ->
//         blocks<256 spin + LayerNorm/GRU (sc partial reads; PLAIN plane writes)
//      B) k_d_comb    : 192 blocks — D GEMM -> flag -> combine/silu (plain out)
//      C) k_e_samp    : 256 blocks — E GEMM (blocks<128) -> flag -> sample
//    Deadlock-free: every block does its GEMM first; grids <= co-residency.
//    All sums/tiles/layouts bit-identical to round 8 (absmax 0.0).

typedef _Float16 f16;
typedef _Float16 f16x8 __attribute__((ext_vector_type(8)));
typedef float f32x4 __attribute__((ext_vector_type(4)));

constexpr int kB = 256, kN1 = 1024, kG3N = 3072, kActD = 6, kT = 64;
constexpr float kLoScale = 4096.f;
constexpr float kLoInv = 1.f / 4096.f;

// ---- coherent (cross-XCD via MALL) accessors for WITHIN-launch data ----
__device__ __forceinline__ float lda_sc(const float* p) {
  return __hip_atomic_load(p, __ATOMIC_RELAXED, __HIP_MEMORY_SCOPE_AGENT);
}
__device__ __forceinline__ void stg_sc(float* p, float v) {
  __hip_atomic_store(p, v, __ATOMIC_RELAXED, __HIP_MEMORY_SCOPE_AGENT);
}
__device__ __forceinline__ int aadd(int* p, int v) {
  return __hip_atomic_fetch_add(p, v, __ATOMIC_RELAXED, __HIP_MEMORY_SCOPE_AGENT);
}
__device__ __forceinline__ int ald(int* p) {
  return __hip_atomic_load(p, __ATOMIC_RELAXED, __HIP_MEMORY_SCOPE_AGENT);
}

__device__ __forceinline__ void wr_planes(f16* hi, f16* lo, size_t i, float x) {
  f16 h = (f16)x;
  hi[i] = h;
  lo[i] = (f16)((x - (float)h) * kLoScale);
}

// plain cacheable DMA (operands cross launch boundaries -> L2-coherent)
__device__ __forceinline__ void glds16(const f16* g, f16* l) {
  __builtin_amdgcn_global_load_lds(
      (const __attribute__((address_space(1))) unsigned int*)g,
      (__attribute__((address_space(3))) unsigned int*)l, 16, 0, 0);
}

// ---------------------------------------------------------- LDS structures
struct GemmLDS { f16 As[3][2][8][64][8]; f16 Ws[3][2][4][64][8]; };  // 72 KB
struct GruLDS  { float sh[kG3N]; float red[8]; };                    // 12.3 KB
struct SmpLDS  { float skl[32]; int sidx[32]; };                     // 256 B
union GGLDS { GemmLDS g; GruLDS r; };
union ESLDS { GemmLDS g; SmpLDS s; };

// ------------------------------------------------------------- MFMA GEMM ----
// 256 threads (4 waves, 2m x 2n), tile 128x64, BK=32. Ring-3 LDS with counted
// vmcnt(6): 2 DMA batches in flight across K-iters (round-8 verified).
// Operands plain (L2). Output sc0sc1 at 64B granule (within-launch consumer).
__device__ void dev_mgemm(GemmLDS& L, const f16* A1h, const f16* A1l,
                          const f16* A2h, const f16* A2l,
                          const f16* Wph, const f16* Wpl, float* outF,
                          int cols1, int K, int Nout, int k0, int klen,
                          int bx, int by, int pstride, int pidx) {
  const int m0 = bx * 128, n0 = by * 64;
  const int tid = threadIdx.x, wave = tid >> 6, lane = tid & 63;
  const int rlo = lane & 15, khi = (lane >> 4) * 8;
  const int wmf = (wave & 1) * 4, wnf = (wave >> 1) * 2;

  f32x4 acc1[4][2], acc2[4][2];
#pragma unroll
  for (int i = 0; i < 4; ++i)
#pragma unroll
    for (int j = 0; j < 2; ++j)
#pragma unroll
      for (int r = 0; r < 4; ++r) { acc1[i][j][r] = 0.f; acc2[i][j][r] = 0.f; }

  auto issueTile = [&](int it, int buf) {   // 6 DMAs per wave
    const int kg = k0 + it * 32;
    const f16 *h, *l; int rs, cb;
    if (kg < cols1) { h = A1h; l = A1l; rs = cols1; cb = kg; }
    else { h = A2h; l = A2l; rs = K - cols1; cb = kg - cols1; }
#pragma unroll
    for (int i = 0; i < 2; ++i) {
      const int mf = wave * 2 + i;
      const size_t go = (size_t)(m0 + mf * 16 + rlo) * rs + cb + khi;
      glds16(h + go, &L.As[buf][0][mf][0][0]);
      glds16(l + go, &L.As[buf][1][mf][0][0]);
    }
    const size_t wo = (size_t)(n0 + wave * 16 + rlo) * K + kg + khi;
    glds16(Wph + wo, &L.Ws[buf][0][wave][0][0]);
    glds16(Wpl + wo, &L.Ws[buf][1][wave][0][0]);
  };

  const int niter = klen >> 5;
  issueTile(0, 0);
  if (niter > 1) issueTile(1, 1);
#pragma unroll 1
  for (int it = 0; it < niter; ++it) {
    const int buf = it % 3;
    if (it + 1 < niter) {
      asm volatile("s_waitcnt vmcnt(6)" ::: "memory");   // batch `it` complete
    } else {
      asm volatile("s_waitcnt vmcnt(0)" ::: "memory");
    }
    __builtin_amdgcn_s_barrier();
    asm volatile("" ::: "memory");
    if (it + 2 < niter) issueTile(it + 2, (it + 2) % 3);
    f16x8 Af[4][2], Wf[2][2];
#pragma unroll
    for (int mf = 0; mf < 4; ++mf) {
      Af[mf][0] = *(const f16x8*)&L.As[buf][0][wmf + mf][lane][0];
      Af[mf][1] = *(const f16x8*)&L.As[buf][1][wmf + mf][lane][0];
    }
#pragma unroll
    for (int nf = 0; nf < 2; ++nf) {
      Wf[nf][0] = *(const f16x8*)&L.Ws[buf][0][wnf + nf][lane][0];
      Wf[nf][1] = *(const f16x8*)&L.Ws[buf][1][wnf + nf][lane][0];
    }
#pragma unroll
    for (int mf = 0; mf < 4; ++mf)
#pragma unroll
      for (int nf = 0; nf < 2; ++nf) {
        acc1[mf][nf] = __builtin_amdgcn_mfma_f32_16x16x32_f16(Af[mf][0], Wf[nf][0], acc1[mf][nf], 0, 0, 0);
        acc2[mf][nf] = __builtin_amdgcn_mfma_f32_16x16x32_f16(Af[mf][0], Wf[nf][1], acc2[mf][nf], 0, 0, 0);
        acc2[mf][nf] = __builtin_amdgcn_mfma_f32_16x16x32_f16(Af[mf][1], Wf[nf][0], acc2[mf][nf], 0, 0, 0);
      }
  }
  __syncthreads();
  const int orow = m0 + (wave & 1) * 64, ocol = n0 + (wave >> 1) * 32;
#pragma unroll
  for (int mf = 0; mf < 4; ++mf)
#pragma unroll
    for (int nf = 0; nf < 2; ++nf)
#pragma unroll
      for (int r = 0; r < 4; ++r) {
        const int row = orow + mf * 16 + (lane >> 4) * 4 + r;
        const int col = ocol + nf * 16 + rlo;
        const int o = row * Nout + col;
        float* dst = outF + ((size_t)(o >> 4) * pstride + pidx) * 16 + (o & 15);
        stg_sc(dst, acc1[mf][nf][r] + acc2[mf][nf][r] * kLoInv);
      }
}

// flag helpers: producer drains sc stores then bumps; consumer spins.
__device__ __forceinline__ void flag_bump(int* ctr) {
  asm volatile("s_waitcnt vmcnt(0)" ::: "memory");   // per-wave drain
  __syncthreads();                                   // all waves drained
  if (threadIdx.x == 0) aadd(ctr, 1);
}
__device__ __forceinline__ void spin_ge(int* p, int tgt) {
  if (threadIdx.x == 0) {
    int guard = 0;
    while (ald(p) < tgt) {
      __builtin_amdgcn_s_sleep(4);
      if (++guard > (1 << 17)) break;   // fast-fail, no wedge
    }
  }
  __syncthreads();
}

// W-panel pair clustering: tasks 2r/2r+1 (bx=0/1, same W panel) -> same XCD
__device__ __forceinline__ int permW(int B2, int pairsPerCls) {
  const int cls = B2 & 7, k = B2 >> 3;
  return ((cls * pairsPerCls + (k >> 1)) << 1) | (k & 1);
}

// =================== launch A: gates GEMM + LayerNorm/GRU ===================
struct GGArgs {
  const f16 *h1h, *h1l, *bh_r, *bl_r;          // A operands (plain, cross-launch)
  const f16 *WfTh, *WfTl, *WgBh, *WgBl;
  float* Pg;                                    // sc partials (4-part, 64B granule)
  const float *bfused, *lns, *lnb, *obs;
  float* bbuf;
  f16 *bh_w, *bl_w, *onh, *onl;
  int* ctr;                                     // [bx]: +bx*16
  int t;
};

__global__ __launch_bounds__(256, 2) void k_gates_gru(GGArgs a) {
  __shared__ GGLDS L;
  const int t = a.t;
  {
    const int task = permW(blockIdx.x, 24);
    const int j = task / 96, r = task % 96, bx = r & 1, by = r >> 1;
    const bool top = (j < 2);
    dev_mgemm(L.g, top ? a.h1h : a.bh_r, top ? a.h1l : a.bl_r, nullptr, nullptr,
              top ? a.WfTh : a.WgBh, top ? a.WfTl : a.WgBl,
              a.Pg, 1024, 1024, kG3N, (j & 1) * 512, 512, bx, by, 4, j);
    flag_bump(a.ctr + bx * 16);
  }
  const int b = blockIdx.x;
  if (b >= kB) return;
  spin_ge(a.ctr + (b >> 7) * 16, (t + 1) * 192);

  // ---- LayerNorm + GRU (sums 4 gate partials; bit-exact round-8 order) ----
  GruLDS& G = L.r;
  const int tid = threadIdx.x;
  float v[12];
  float sum = 0.f, sq = 0.f;
#pragma unroll
  for (int i = 0; i < 12; ++i) {
    const int j = tid + i * 256;
    const size_t o = (size_t)b * kG3N + j;
    const float* base = a.Pg + ((o >> 4) * 4) * 16 + (o & 15);
    const float q0 = lda_sc(base),      q1 = lda_sc(base + 16);
    const float q2 = lda_sc(base + 32), q3 = lda_sc(base + 48);
    const float s = (((q0 + q1) + q2) + q3) + a.bfused[j];
    v[i] = s; sum += s; sq += s * s;
  }
  if (t < kT - 1) {   // stage next-step obs planes (plain; consumed next launch B)
#pragma unroll
    for (int i = 0; i < 4; ++i) {
      const int j = tid + i * 256;
      wr_planes(a.onh, a.onl, (size_t)b * kN1 + j,
                a.obs[(size_t)(t + 1) * kB * kN1 + (size_t)b * kN1 + j]);
    }
  }
  for (int m = 1; m <= 32; m <<= 1) { sum += __shfl_xor(sum, m); sq += __shfl_xor(sq, m); }
  if ((tid & 63) == 0) { G.red[(tid >> 6) * 2] = sum; G.red[(tid >> 6) * 2 + 1] = sq; }
  __syncthreads();
  float ts = 0.f, tq = 0.f;
  for (int w = 0; w < 4; ++w) { ts += G.red[w * 2]; tq += G.red[w * 2 + 1]; }
  const float mu   = ts * (1.f / kG3N);
  const float var  = tq * (1.f / kG3N) - mu * mu;
  const float rinv = 1.f / sqrtf(var + 1e-3f);
#pragma unroll
  for (int i = 0; i < 12; ++i) {
    const int j = tid + i * 256;
    G.sh[j] = (v[i] - mu) * rinv * a.lns[j] + a.lnb[j];
  }
  __syncthreads();
#pragma unroll
  for (int i = 0; i < 4; ++i) {
    const int j = tid + i * 256;
    const float r = G.sh[j], c = G.sh[kN1 + j], u = G.sh[2 * kN1 + j];
    const float reset = 1.f / (1.f + expf(-r));
    const float cand  = tanhf(reset * c);
    const float upd   = 1.f / (1.f + expf(-(u - 1.f)));   // UPDATE_BIAS = -1
    const size_t o = (size_t)b * kN1 + j;
    const float bn = upd * cand + (1.f - upd) * a.bbuf[o];
    a.bbuf[o] = bn;
    wr_planes(a.bh_w, a.bl_w, o, bn);      // plain: consumed next launch
  }
}

// ====================== launch B: D GEMM + combine/silu =====================
struct DCArgs {
  const f16 *bh, *bl, *oth, *otl;
  const f16 *Wp1Th, *Wp1Tl, *Wo1Th, *Wo1Tl;
  float* PD;                                    // sc partials (6-part)
  const float *bp1, *bo1;
  f16 *hph, *hpl, *hoh, *hol;
  int* ctr;
  int t;
};

__global__ __launch_bounds__(256, 2) void k_d_comb(DCArgs a) {
  __shared__ GemmLDS L;
  const int t = a.t;
  {
    const int task = permW(blockIdx.x, 12);
    const int j = task >> 5, r = task & 31, bx = r & 1, by = r >> 1;
    const f16 *Ah, *Al, *A2h = nullptr, *A2l = nullptr, *Wh, *Wl;
    int K, k0;
    if (j < 2) { Ah = a.bh; Al = a.bl; Wh = a.Wp1Th; Wl = a.Wp1Tl; K = 1024; k0 = j * 512; }
    else { Ah = a.oth; Al = a.otl; A2h = a.bh; A2l = a.bl; Wh = a.Wo1Th; Wl = a.Wo1Tl; K = 2048; k0 = (j - 2) * 512; }
    dev_mgemm(L, Ah, Al, A2h, A2l, Wh, Wl, a.PD, 1024, K, kN1, k0, 512, bx, by, 6, j);
    flag_bump(a.ctr + bx * 16);
  }
  spin_ge(a.ctr, (t + 1) * 96);
  spin_ge(a.ctr + 16, (t + 1) * 96);
  // combine — hp = silu(p0+p1+bp1); ho = silu(p2+p3+p4+p5+bo1) (round-8 order)
#pragma unroll 1
  for (int idx = blockIdx.x; idx < 1024; idx += 192) {
    const int i = idx * 256 + (int)threadIdx.x;
    const float* base = a.PD + ((size_t)(i >> 4) * 6) * 16 + (i & 15);
    const float p0 = lda_sc(base),      p1 = lda_sc(base + 16);
    const float p2 = lda_sc(base + 32), p3 = lda_sc(base + 48);
    const float p4 = lda_sc(base + 64), p5 = lda_sc(base + 80);
    float sp = (p0 + p1) + a.bp1[i & (kN1 - 1)];
    sp = sp * (1.f / (1.f + expf(-sp)));
    wr_planes(a.hph, a.hpl, i, sp);        // plain: consumed next launch
    float so = (((p2 + p3) + p4) + p5) + a.bo1[i & (kN1 - 1)];
    so = so * (1.f / (1.f + expf(-so)));
    wr_planes(a.hoh, a.hol, i, so);
  }
}

// ====================== launch C: E GEMM + sample/loss ======================
struct ESArgs {
  const f16 *hph, *hpl, *hoh, *hol;
  const f16 *Wp2Th, *Wp2Tl, *Wo2Th, *Wo2Tl;
  float* PE;                                    // sc partials (4-part)
  const float *bp2, *bo2, *unz, *acts, *Wi1, *bi1;
  float* out;
  f16 *h1h, *h1l;
  int* ctr;
  int t;
};

__global__ __launch_bounds__(256, 2) void k_e_samp(ESArgs a) {
  __shared__ ESLDS L;
  const int t = a.t;
  if (blockIdx.x < 128) {
    const int task = permW(blockIdx.x, 8);
    const int j = task >> 5, r = task & 31, bx = r & 1, by = r >> 1;
    const bool pr = (j < 2);
    dev_mgemm(L.g, pr ? a.hph : a.hoh, pr ? a.hpl : a.hol, nullptr, nullptr,
              pr ? a.Wp2Th : a.Wo2Th, pr ? a.Wp2Tl : a.Wo2Tl,
              a.PE, 1024, 1024, kN1, (j & 1) * 512, 512, bx, by, 4, j);
    flag_bump(a.ctr + bx * 16);
  }
  const int b = blockIdx.x;
  spin_ge(a.ctr + (b >> 7) * 16, (t + 1) * 64);

  // ---- softmax/unimix/KL + Gumbel argmax + h1 gather (round-8 256-thr) ----
  SmpLDS& S = L.s;
  const int tid = threadIdx.x;
  const float* unz_t = a.unz + (size_t)t * kB * kN1;
  __syncthreads();
#pragma unroll
  for (int c = 0; c < 4; ++c) {
    const int j = c * 256 + tid;
    const int o = b * kN1 + j;
    const float* base = a.PE + ((size_t)(o >> 4) * 4) * 16 + (o & 15);
    const float e0 = lda_sc(base),      e1 = lda_sc(base + 16);
    const float e2 = lda_sc(base + 32), e3 = lda_sc(base + 48);
    float lp = e0 + e1 + a.bp2[j];
    float lo = e2 + e3 + a.bo2[j];
    lp = fminf(fmaxf(lp, -20.f), 20.f);
    lo = fminf(fmaxf(lo, -20.f), 20.f);
    float mp = lp, mo = lo;
    for (int m = 1; m <= 16; m <<= 1) { mp = fmaxf(mp, __shfl_xor(mp, m)); mo = fmaxf(mo, __shfl_xor(mo, m)); }
    const float ep = expf(lp - mp), eo = expf(lo - mo);
    float sp = ep, so = eo;
    for (int m = 1; m <= 16; m <<= 1) { sp += __shfl_xor(sp, m); so += __shfl_xor(so, m); }
    const float pp = (ep / sp) * 0.99f + (0.01f / 32.f);
    const float po = (eo / so) * 0.99f + (0.01f / 32.f);
    float kt = po * (logf(po + 1e-8f) - logf(pp + 1e-8f));
    for (int m = 1; m <= 16; m <<= 1) kt += __shfl_xor(kt, m);
    const float u = unz_t[o];
    const float g = -logf(-logf(u + 1e-6f) + 1e-6f);
    float vv = logf(fmaxf(po, 1e-6f)) + g;
    int ii = j & 31;
    for (int m = 1; m <= 16; m <<= 1) {
      const float vo = __shfl_xor(vv, m);
      const int   io = __shfl_xor(ii, m);
      if (vo > vv || (vo == vv && io < ii)) { vv = vo; ii = io; }   // first-max ties
    }
    if ((tid & 31) == 0) { S.skl[j >> 5] = kt; S.sidx[j >> 5] = ii; }
  }
  __syncthreads();
  if (tid == 0) {
    float kl = 0.f;
    for (int gg = 0; gg < 32; ++gg) kl += S.skl[gg];
    const float dl = fmaxf(kl, 0.1f);
    a.out[(size_t)t * kB + b] = 1.0f * dl + 0.1f * dl;
  }
  if (t < kT - 1) {
    const float* act_next = a.acts + (size_t)(t + 1) * kB * kActD;
#pragma unroll
    for (int c = 0; c < 4; ++c) {
      const int j = c * 256 + tid;
      float s = a.bi1[j];
#pragma unroll
      for (int gg = 0; gg < 32; ++gg)
        s += a.Wi1[(size_t)(gg * 32 + S.sidx[gg]) * kN1 + j];
#pragma unroll
      for (int k = 0; k < kActD; ++k)
        s += act_next[b * kActD + k] * a.Wi1[(size_t)(kN1 + k) * kN1 + j];
      s = s * (1.f / (1.f + expf(-s)));
      wr_planes(a.h1h, a.h1l, (size_t)b * kN1 + j, s);   // plain: next launch A
    }
  }
}

// ------------------------------------------------------------- prologue -----
struct MJob {
  const f16 *A1h, *A1l, *A2h, *A2l;
  const f16 *Wph, *Wpl;
  float* outF;
  int cols1, K, Nout, k0, klen, ny, pstride, pidx;
};
struct MJobs { MJob j[6]; };

__global__ __launch_bounds__(256, 2) void k_mgemm(MJobs js) {
  const MJob jb = js.j[blockIdx.z];
  if ((int)blockIdx.y >= jb.ny) return;
  __shared__ GemmLDS L;
  dev_mgemm(L, jb.A1h, jb.A1l, jb.A2h, jb.A2l, jb.Wph, jb.Wpl, jb.outF,
            jb.cols1, jb.K, jb.Nout, jb.k0, jb.klen, blockIdx.x, blockIdx.y,
            jb.pstride, jb.pidx);
}

__global__ __launch_bounds__(256) void k_conv(const float* src, f16* dh, f16* dl) {
  const size_t i = (size_t)blockIdx.x * 256 + threadIdx.x;
  wr_planes(dh, dl, i, src[i]);
}

__global__ __launch_bounds__(256) void k_convT(const float* src, int rowoff, int srcN,
                                               int K, f16* dh, f16* dl) {
  __shared__ float T[64][65];
  const int k0 = blockIdx.x * 64, n0 = blockIdx.y * 64;
  const int tx = threadIdx.x & 63, ty = threadIdx.x >> 6;
#pragma unroll 4
  for (int i = 0; i < 16; ++i) {
    const int k = ty * 16 + i;
    T[k][tx] = src[(size_t)(rowoff + k0 + k) * srcN + n0 + tx];
  }
  __syncthreads();
#pragma unroll 4
  for (int i = 0; i < 16; ++i) {
    const int n = ty * 16 + i;
    const float x = T[tx][n];
    const size_t o = (size_t)(n0 + n) * K + k0 + tx;
    f16 h = (f16)x;
    dh[o] = h;
    dl[o] = (f16)((x - (float)h) * kLoScale);
  }
}

__global__ __launch_bounds__(256) void k_bfused(const float* Wg, const float* bi2, float* bf) {
  const int n = blockIdx.x * 256 + threadIdx.x;
  float s = 0.f;
  for (int j = 0; j < 1024; ++j) s += bi2[j] * Wg[(size_t)j * kG3N + n];
  bf[n] = s;
}

__global__ __launch_bounds__(256) void k_setup(const float* b0, float* bbuf, f16* bh, f16* bl) {
  const size_t i = (size_t)blockIdx.x * 256 + threadIdx.x;
  const float b = b0[i];
  bbuf[i] = b;
  wr_planes(bh, bl, i, b);
}

__global__ void k_zero(int* p) {
  const int i = blockIdx.x * 256 + threadIdx.x;
  if (i < 512) p[i] = 0;
}

__global__ __launch_bounds__(256) void k_finish0(const float* P, const float* Wi1,
    const float* bi1, const float* act0, f16* h1h, f16* h1l) {
  const int b = blockIdx.y;
  const int j = blockIdx.x * 256 + threadIdx.x;
  __shared__ float sact[kActD];
  if (threadIdx.x < kActD) sact[threadIdx.x] = act0[b * kActD + threadIdx.x];
  __syncthreads();
  float s = P[(size_t)b * kN1 + j] + bi1[j];
#pragma unroll
  for (int k = 0; k < kActD; ++k) s += sact[k] * Wi1[(size_t)(kN1 + k) * kN1 + j];
  s = s * (1.f / (1.f + expf(-s)));
  wr_planes(h1h, h1l, (size_t)b * kN1 + j, s);
}

// ---------------------------------------------------------------------------
extern "C" void kernel_launch(void* const* d_in, const int* in_sizes, int n_in,
                              void* d_out, int out_size, void* d_ws, size_t ws_size,
                              hipStream_t stream) {
  const float* b0   = (const float*)d_in[0];
  const float* z0   = (const float*)d_in[1];
  const float* acts = (const float*)d_in[2];
  const float* obs  = (const float*)d_in[3];
  const float* unz  = (const float*)d_in[4];
  const float* Wi1  = (const float*)d_in[5];
  const float* bi1  = (const float*)d_in[6];
  const float* Wi2  = (const float*)d_in[7];
  const float* bi2  = (const float*)d_in[8];
  const float* Wg   = (const float*)d_in[9];
  const float* lns  = (const float*)d_in[10];
  const float* lnb  = (const float*)d_in[11];
  const float* Wo1  = (const float*)d_in[12];
  const float* bo1  = (const float*)d_in[13];
  const float* Wo2  = (const float*)d_in[14];
  const float* bo2  = (const float*)d_in[15];
  const float* Wp1  = (const float*)d_in[16];
  const float* bp1  = (const float*)d_in[17];
  const float* Wp2  = (const float*)d_in[18];
  const float* bp2  = (const float*)d_in[19];
  float* out = (float*)d_out;

  char* wsb = (char*)d_ws;
  size_t off = 0;
  auto allocB = [&](size_t bytes) { char* p = wsb + off; off += (bytes + 255) & ~(size_t)255; return p; };
  const size_t PL = (size_t)kB * kN1;
  const size_t S3 = (size_t)kB * kG3N;
  const size_t W1 = (size_t)kN1 * kN1;

  // region A: gate partials (4 x 256x3072 fp32 = 12 MB) — overlays Wfused_tmp
  float* Pg = (float*)allocB(4 * S3 * 4);
  float* Wfused_tmp = Pg;
  // region B: WgT planes (prologue-only) — overlays PD (6 MB) + PE (4 MB)
  f16* WgTh = (f16*)allocB(W1 * 3 * 2);
  f16* WgTl = (f16*)allocB(W1 * 3 * 2);
  float* PD = (float*)WgTh;
  float* PE = (float*)WgTl;
  // persistent planes / state
  f16* h1h = (f16*)allocB(PL * 2);  f16* h1l = (f16*)allocB(PL * 2);
  f16* bh  = (f16*)allocB(PL * 2);  f16* bl  = (f16*)allocB(PL * 2);
  f16* hph = (f16*)allocB(PL * 2);  f16* hpl = (f16*)allocB(PL * 2);
  f16* hoh = (f16*)allocB(PL * 2);  f16* hol = (f16*)allocB(PL * 2);
  f16* o0h = (f16*)allocB(PL * 2);  f16* o0l = (f16*)allocB(PL * 2);
  f16* o1h = (f16*)allocB(PL * 2);  f16* o1l = (f16*)allocB(PL * 2);
  f16* z0h = (f16*)allocB(PL * 2);  f16* z0l = (f16*)allocB(PL * 2);
  float* bbuf   = (float*)allocB(PL * 4);
  float* bfused = (float*)allocB((size_t)kG3N * 4);
  // weight planes
  f16* WfTh = (f16*)allocB(W1 * 3 * 2);  f16* WfTl = (f16*)allocB(W1 * 3 * 2);
  f16* WgBh = (f16*)allocB(W1 * 3 * 2);  f16* WgBl = (f16*)allocB(W1 * 3 * 2);
  f16* Wi2h = (f16*)allocB(W1 * 2);      f16* Wi2l = (f16*)allocB(W1 * 2);
  f16* Wi1Th = (f16*)allocB(W1 * 2);     f16* Wi1Tl = (f16*)allocB(W1 * 2);
  f16* Wo1Th = (f16*)allocB(W1 * 2 * 2); f16* Wo1Tl = (f16*)allocB(W1 * 2 * 2);
  f16* Wp1Th = (f16*)allocB(W1 * 2);     f16* Wp1Tl = (f16*)allocB(W1 * 2);
  f16* Wp2Th = (f16*)allocB(W1 * 2);     f16* Wp2Tl = (f16*)allocB(W1 * 2);
  f16* Wo2Th = (f16*)allocB(W1 * 2);     f16* Wo2Tl = (f16*)allocB(W1 * 2);
  int* cnt = (int*)allocB(4096);   // flag lines: A@0/16, B@32/48, C@64/80

  // ================= prologue (verified, unchanged) =================
  k_convT<<<dim3(16, 48), 256, 0, stream>>>(Wg, 0, kG3N, 1024, WgTh, WgTl);
  k_convT<<<dim3(16, 48), 256, 0, stream>>>(Wg, 1024, kG3N, 1024, WgBh, WgBl);
  k_convT<<<dim3(16, 16), 256, 0, stream>>>(Wi1, 0, kN1, 1024, Wi1Th, Wi1Tl);
  k_convT<<<dim3(32, 16), 256, 0, stream>>>(Wo1, 0, kN1, 2048, Wo1Th, Wo1Tl);
  k_convT<<<dim3(16, 16), 256, 0, stream>>>(Wp1, 0, kN1, 1024, Wp1Th, Wp1Tl);
  k_convT<<<dim3(16, 16), 256, 0, stream>>>(Wp2, 0, kN1, 1024, Wp2Th, Wp2Tl);
  k_convT<<<dim3(16, 16), 256, 0, stream>>>(Wo2, 0, kN1, 1024, Wo2Th, Wo2Tl);
  k_conv<<<dim3(4096), 256, 0, stream>>>(Wi2, Wi2h, Wi2l);
  k_bfused<<<dim3(12), 256, 0, stream>>>(Wg, bi2, bfused);
  {  // Wfused = Wi2 @ WgTop (plain layout: pstride 1)
    MJobs J{};
    J.j[0] = { Wi2h, Wi2l, nullptr, nullptr, WgTh, WgTl, Wfused_tmp, 1024, 1024, kG3N, 0, 1024, 48, 1, 0 };
    k_mgemm<<<dim3(8, 48, 1), 256, 0, stream>>>(J);
  }
  k_convT<<<dim3(16, 48), 256, 0, stream>>>(Wfused_tmp, 0, kG3N, 1024, WfTh, WfTl);
  // WgT region dead from here -> PD/PE reuse it
  k_setup<<<dim3(1024), 256, 0, stream>>>(b0, bbuf, bh, bl);
  k_conv<<<dim3(1024), 256, 0, stream>>>(z0, z0h, z0l);
  k_conv<<<dim3(1024), 256, 0, stream>>>(obs, o0h, o0l);    // obs[0]
  k_zero<<<dim3(2), 256, 0, stream>>>(cnt);
  {  // h1(t=0): z0 @ Wi1Top -> PD (plain layout), then finisher
    MJobs J{};
    J.j[0] = { z0h, z0l, nullptr, nullptr, Wi1Th, Wi1Tl, PD, 1024, 1024, kN1, 0, 1024, 16, 1, 0 };
    k_mgemm<<<dim3(2, 16, 1), 256, 0, stream>>>(J);
  }
  k_finish0<<<dim3(4, kB), 256, 0, stream>>>(PD, Wi1, bi1, acts, h1h, h1l);

  // ================= the scan: 3 launches per step =================
  for (int t = 0; t < kT; ++t) {
    f16* oth = (t & 1) ? o1h : o0h;
    f16* otl = (t & 1) ? o1l : o0l;
    f16* onh = (t & 1) ? o0h : o1h;
    f16* onl = (t & 1) ? o0l : o1l;

    GGArgs A;
    A.h1h = h1h; A.h1l = h1l; A.bh_r = bh; A.bl_r = bl;
    A.WfTh = WfTh; A.WfTl = WfTl; A.WgBh = WgBh; A.WgBl = WgBl;
    A.Pg = Pg; A.bfused = bfused; A.lns = lns; A.lnb = lnb; A.obs = obs;
    A.bbuf = bbuf; A.bh_w = bh; A.bl_w = bl; A.onh = onh; A.onl = onl;
    A.ctr = cnt; A.t = t;
    k_gates_gru<<<dim3(384), 256, 0, stream>>>(A);

    DCArgs D;
    D.bh = bh; D.bl = bl; D.oth = oth; D.otl = otl;
    D.Wp1Th = Wp1Th; D.Wp1Tl = Wp1Tl; D.Wo1Th = Wo1Th; D.Wo1Tl = Wo1Tl;
    D.PD = PD; D.bp1 = bp1; D.bo1 = bo1;
    D.hph = hph; D.hpl = hpl; D.hoh = hoh; D.hol = hol;
    D.ctr = cnt + 32; D.t = t;
    k_d_comb<<<dim3(192), 256, 0, stream>>>(D);

    ESArgs E;
    E.hph = hph; E.hpl = hpl; E.hoh = hoh; E.hol = hol;
    E.Wp2Th = Wp2Th; E.Wp2Tl = Wp2Tl; E.Wo2Th = Wo2Th; E.Wo2Tl = Wo2Tl;
    E.PE = PE; E.bp2 = bp2; E.bo2 = bo2; E.unz = unz; E.acts = acts;
    E.Wi1 = Wi1; E.bi1 = bi1; E.out = out; E.h1h = h1h; E.h1l = h1l;
    E.ctr = cnt + 64; E.t = t;
    k_e_samp<<<dim3(256), 256, 0, stream>>>(E);
  }
}